// Round 2
// baseline (310.951 us; speedup 1.0000x reference)
//
#include <hip/hip_runtime.h>
#include <hip/hip_bf16.h>

// B=2, S=2048, D=1024, H=8, HD=128, RANK=4.
// Device I/O buffers are FP32 (per reference dtypes; npz sizes confirm).
// Internal pipeline: convert to bf16 in d_ws, bf16 MFMA with fp32 accum.

typedef __bf16 bf8_t __attribute__((ext_vector_type(8)));
typedef float f32x4 __attribute__((ext_vector_type(4)));

#define MFMA_BF16(a, b, c) __builtin_amdgcn_mfma_f32_16x16x32_bf16((a), (b), (c), 0, 0, 0)

__device__ __forceinline__ void gload_lds16(const void* g, void* l) {
  __builtin_amdgcn_global_load_lds(
      (const __attribute__((address_space(1))) void*)g,
      (__attribute__((address_space(3))) void*)l, 16, 0, 0);
}

// ---------------------------------------------------------------------------
// Kernel 0: fp32 -> bf16 conversion. blockIdx.y selects tensor
// (0=hidden_states 4M elems, 1..4 = Wq,Wk,Wv,Wo 1M each). 8 elems/thread.
// ---------------------------------------------------------------------------
__global__ __launch_bounds__(256) void cvt5_k(
    const float* __restrict__ s0, const float* __restrict__ s1,
    const float* __restrict__ s2, const float* __restrict__ s3,
    const float* __restrict__ s4, __bf16* __restrict__ d0,
    __bf16* __restrict__ d1, __bf16* __restrict__ d2, __bf16* __restrict__ d3,
    __bf16* __restrict__ d4) {
  const int which = blockIdx.y;
  const float* s = (which == 0) ? s0 : (which == 1) ? s1 : (which == 2) ? s2
                   : (which == 3) ? s3 : s4;
  __bf16* d = (which == 0) ? d0 : (which == 1) ? d1 : (which == 2) ? d2
              : (which == 3) ? d3 : d4;
  const int n = (which == 0) ? (4096 * 1024) : (1024 * 1024);
  const int i = (blockIdx.x * 256 + threadIdx.x) * 8;
  if (i >= n) return;
  float4 a = *(const float4*)(s + i);
  float4 b = *(const float4*)(s + i + 4);
  bf8_t r;
  r[0] = (__bf16)a.x; r[1] = (__bf16)a.y; r[2] = (__bf16)a.z; r[3] = (__bf16)a.w;
  r[4] = (__bf16)b.x; r[5] = (__bf16)b.y; r[6] = (__bf16)b.z; r[7] = (__bf16)b.w;
  *(bf8_t*)(d + i) = r;
}

// ---------------------------------------------------------------------------
// GEMM tile body: C[128,128] = A[128,K] * W[128(cols),K]^T (NT, contraction
// along contiguous K). 256 threads = 4 waves (2x2), each wave a 64x64
// sub-tile = 4x4 fragments, BK=64. LDS linear [128][64] for global_load_lds.
// ---------------------------------------------------------------------------
__device__ __forceinline__ void gemm_tile(const __bf16* __restrict__ Abase,
                                          const __bf16* __restrict__ Wbase,
                                          int K, __bf16* sA, __bf16* sB,
                                          f32x4 acc[4][4]) {
  const int tid = threadIdx.x;
  const int wave = tid >> 6, lane = tid & 63;
  const int wr = (wave >> 1) * 64, wc = (wave & 1) * 64;
  const int lrow = lane >> 3, lchunk = lane & 7;  // 8 rows x 8 chunks / issue

  for (int m = 0; m < 4; ++m)
    for (int n = 0; n < 4; ++n)
      acc[m][n] = f32x4{0.f, 0.f, 0.f, 0.f};

  for (int k0 = 0; k0 < K; k0 += 64) {
    for (int i = 0; i < 4; ++i) {
      const int rbase = i * 32 + wave * 8;
      gload_lds16(Abase + (size_t)(rbase + lrow) * K + k0 + lchunk * 8,
                  sA + rbase * 64);
      gload_lds16(Wbase + (size_t)(rbase + lrow) * K + k0 + lchunk * 8,
                  sB + rbase * 64);
    }
    __syncthreads();

    for (int kk = 0; kk < 2; ++kk) {
      bf8_t af[4], bfr[4];
      const int koff = kk * 32 + (lane >> 4) * 8;
      for (int m = 0; m < 4; ++m)
        af[m] = *(const bf8_t*)&sA[(wr + m * 16 + (lane & 15)) * 64 + koff];
      for (int n = 0; n < 4; ++n)
        bfr[n] = *(const bf8_t*)&sB[(wc + n * 16 + (lane & 15)) * 64 + koff];
      for (int m = 0; m < 4; ++m)
        for (int n = 0; n < 4; ++n)
          acc[m][n] = MFMA_BF16(af[m], bfr[n], acc[m][n]);
    }
    __syncthreads();
  }
}

// ---------------------------------------------------------------------------
// Kernel 1: QKV projections (bf16 in, bf16 out). blockIdx.z selects weight.
// ---------------------------------------------------------------------------
__global__ __launch_bounds__(256) void gemm_qkv_k(
    const __bf16* __restrict__ X, const __bf16* __restrict__ Wq,
    const __bf16* __restrict__ Wk, const __bf16* __restrict__ Wv,
    __bf16* __restrict__ Qb, __bf16* __restrict__ Kb, __bf16* __restrict__ Vb) {
  __shared__ __bf16 sA[128 * 64];
  __shared__ __bf16 sB[128 * 64];
  const int bcol = blockIdx.x, brow = blockIdx.y, z = blockIdx.z;
  const __bf16* W = (z == 0) ? Wq : (z == 1) ? Wk : Wv;
  __bf16* C = (z == 0) ? Qb : (z == 1) ? Kb : Vb;
  const int K = 1024, N = 1024;
  f32x4 acc[4][4];
  gemm_tile(X + (size_t)brow * 128 * K, W + (size_t)bcol * 128 * K, K, sA, sB, acc);

  const int lane = threadIdx.x & 63, wave = threadIdx.x >> 6;
  const int wr = (wave >> 1) * 64, wc = (wave & 1) * 64;
  const int row0 = brow * 128 + wr + (lane >> 4) * 4;  // D: col=lane&15,
  const int col0 = bcol * 128 + wc + (lane & 15);      // row=(lane>>4)*4+reg
  for (int m = 0; m < 4; ++m)
    for (int n = 0; n < 4; ++n)
      for (int j = 0; j < 4; ++j)
        C[(size_t)(row0 + m * 16 + j) * N + col0 + n * 16] = (__bf16)acc[m][n][j];
}

// ---------------------------------------------------------------------------
// Kernel 2: LoRA down: tmp[s][r] = sum_d control[s][d]*down[r][d]. FP32 in.
// One wave per row s; 16 floats per lane; full-wave shuffle reduce.
// ---------------------------------------------------------------------------
__global__ __launch_bounds__(256) void lora_down_k(
    const float* __restrict__ ctrl, const float* __restrict__ down,
    float* __restrict__ tmp) {
  const int tid = threadIdx.x, wave = tid >> 6, lane = tid & 63;
  const int s = blockIdx.x * 4 + wave;
  const float* cp = ctrl + (size_t)s * 1024 + lane * 16;
  float4 c[4];
  for (int i = 0; i < 4; ++i) c[i] = *(const float4*)(cp + i * 4);
  for (int r = 0; r < 4; ++r) {
    const float* dp = down + r * 1024 + lane * 16;
    float acc = 0.f;
    for (int i = 0; i < 4; ++i) {
      float4 dv = *(const float4*)(dp + i * 4);
      acc += c[i].x * dv.x + c[i].y * dv.y + c[i].z * dv.z + c[i].w * dv.w;
    }
    for (int off = 32; off > 0; off >>= 1) acc += __shfl_xor(acc, off);
    if (lane == 0) tmp[s * 4 + r] = acc;
  }
}

// ---------------------------------------------------------------------------
// Kernel 3: flash attention (bf16 in/out, fp32 softmax+accum).
// One block per (64 q-rows, b*h); 4 waves, wave w owns 16 q-rows.
//   sK[64][136] padded; sV[128][72] transposed; sP[wave][16][72] P roundtrip.
// ---------------------------------------------------------------------------
__global__ __launch_bounds__(256) void flash_attn_k(
    const __bf16* __restrict__ Qg, const __bf16* __restrict__ Kg,
    const __bf16* __restrict__ Vg, __bf16* __restrict__ Og) {
  const int S = 2048, D = 1024;
  __shared__ __bf16 sK[64 * 136];
  __shared__ __bf16 sV[128 * 72];
  __shared__ __bf16 sP[4][16 * 72];
  const int qt = blockIdx.x, bh = blockIdx.y;
  const int b = bh >> 3, h = bh & 7;
  const int tid = threadIdx.x, wave = tid >> 6, lane = tid & 63;
  const size_t base = (size_t)b * S * D + (size_t)h * 128;
  const int q0 = qt * 64 + wave * 16;
  const int koff = (lane >> 4) * 8;

  bf8_t qf[4];
  {
    const __bf16* qp = Qg + base + (size_t)(q0 + (lane & 15)) * D + koff;
    for (int d0 = 0; d0 < 4; ++d0) qf[d0] = *(const bf8_t*)(qp + d0 * 32);
  }

  f32x4 o[8];
  for (int f = 0; f < 8; ++f) o[f] = f32x4{0.f, 0.f, 0.f, 0.f};
  float mrow[4] = {-1e30f, -1e30f, -1e30f, -1e30f};
  float lrow[4] = {0.f, 0.f, 0.f, 0.f};
  const float scale = 0.08838834764831845f;  // 1/sqrt(128)

  const int sr = tid >> 4, scnk = tid & 15;

  for (int kv0 = 0; kv0 < S; kv0 += 64) {
    for (int i = 0; i < 4; ++i) {
      const int r = i * 16 + sr;
      int4 kd = *(const int4*)(Kg + base + (size_t)(kv0 + r) * D + scnk * 8);
      *(int4*)&sK[r * 136 + scnk * 8] = kd;
      int4 vd = *(const int4*)(Vg + base + (size_t)(kv0 + r) * D + scnk * 8);
      const __bf16* e = (const __bf16*)&vd;
      for (int j = 0; j < 8; ++j) sV[(scnk * 8 + j) * 72 + r] = e[j];
    }
    __syncthreads();

    f32x4 s4[4];
    for (int n = 0; n < 4; ++n) {
      f32x4 a_ = f32x4{0.f, 0.f, 0.f, 0.f};
      const __bf16* kp = &sK[(n * 16 + (lane & 15)) * 136 + koff];
      for (int d0 = 0; d0 < 4; ++d0)
        a_ = MFMA_BF16(qf[d0], *(const bf8_t*)(kp + d0 * 32), a_);
      s4[n] = a_;
    }
    for (int n = 0; n < 4; ++n) s4[n] = s4[n] * scale;

    float tmax[4];
    for (int j = 0; j < 4; ++j)
      tmax[j] = fmaxf(fmaxf(s4[0][j], s4[1][j]), fmaxf(s4[2][j], s4[3][j]));
    for (int off = 1; off < 16; off <<= 1)
      for (int j = 0; j < 4; ++j)
        tmax[j] = fmaxf(tmax[j], __shfl_xor(tmax[j], off));
    float sc_[4], rs[4];
    for (int j = 0; j < 4; ++j) {
      float mnew = fmaxf(mrow[j], tmax[j]);
      sc_[j] = __expf(mrow[j] - mnew);
      mrow[j] = mnew;
      rs[j] = 0.f;
    }
    for (int n = 0; n < 4; ++n)
      for (int j = 0; j < 4; ++j) {
        float p = __expf(s4[n][j] - mrow[j]);
        s4[n][j] = p;
        rs[j] += p;
      }
    for (int off = 1; off < 16; off <<= 1)
      for (int j = 0; j < 4; ++j) rs[j] += __shfl_xor(rs[j], off);
    for (int j = 0; j < 4; ++j) lrow[j] = lrow[j] * sc_[j] + rs[j];
    for (int f = 0; f < 8; ++f)
      for (int j = 0; j < 4; ++j) o[f][j] *= sc_[j];

    __bf16* pw = &sP[wave][0];
    for (int n = 0; n < 4; ++n)
      for (int j = 0; j < 4; ++j)
        pw[((lane >> 4) * 4 + j) * 72 + n * 16 + (lane & 15)] = (__bf16)s4[n][j];

    for (int kk = 0; kk < 2; ++kk) {
      bf8_t pa = *(const bf8_t*)&pw[(lane & 15) * 72 + kk * 32 + koff];
      for (int f = 0; f < 8; ++f) {
        bf8_t vb = *(const bf8_t*)&sV[(f * 16 + (lane & 15)) * 72 + kk * 32 + koff];
        o[f] = MFMA_BF16(pa, vb, o[f]);
      }
    }
    __syncthreads();
  }

  float inv[4];
  for (int j = 0; j < 4; ++j) inv[j] = 1.f / lrow[j];
  for (int f = 0; f < 8; ++f)
    for (int j = 0; j < 4; ++j)
      Og[base + (size_t)(q0 + (lane >> 4) * 4 + j) * D + f * 16 + (lane & 15)] =
          (__bf16)(o[f][j] * inv[j]);
}

// ---------------------------------------------------------------------------
// Kernel 4: output projection + bias + LoRA-up. bf16 GEMM, fp32 epilogue/out.
// out[s][e] = attn[s][:].Wo[e][:] + bo[e] + sum_r tmp[s][r]*lup[e][r]
// ---------------------------------------------------------------------------
__global__ __launch_bounds__(256) void gemm_out_k(
    const __bf16* __restrict__ A, const __bf16* __restrict__ Wo,
    const float* __restrict__ bo, const float* __restrict__ lup,
    const float* __restrict__ tmp, float* __restrict__ out) {
  __shared__ __bf16 sA[128 * 64];
  __shared__ __bf16 sB[128 * 64];
  const int bcol = blockIdx.x, brow = blockIdx.y;
  const int K = 1024, N = 1024;
  f32x4 acc[4][4];
  gemm_tile(A + (size_t)brow * 128 * K, Wo + (size_t)bcol * 128 * K, K, sA, sB, acc);

  const int lane = threadIdx.x & 63, wave = threadIdx.x >> 6;
  const int wr = (wave >> 1) * 64, wc = (wave & 1) * 64;
  for (int n = 0; n < 4; ++n) {
    const int col = bcol * 128 + wc + n * 16 + (lane & 15);
    const float bias = bo[col];
    const float u0 = lup[col * 4 + 0], u1 = lup[col * 4 + 1];
    const float u2 = lup[col * 4 + 2], u3 = lup[col * 4 + 3];
    for (int m = 0; m < 4; ++m)
      for (int j = 0; j < 4; ++j) {
        const int row = brow * 128 + wr + m * 16 + (lane >> 4) * 4 + j;
        const float* t = tmp + row * 4;
        float v = acc[m][n][j] + bias + t[0] * u0 + t[1] * u1 + t[2] * u2 + t[3] * u3;
        out[(size_t)row * N + col] = v;
      }
  }
}

// ---------------------------------------------------------------------------
extern "C" void kernel_launch(void* const* d_in, const int* in_sizes, int n_in,
                              void* d_out, int out_size, void* d_ws, size_t ws_size,
                              hipStream_t stream) {
  (void)in_sizes; (void)n_in; (void)out_size; (void)ws_size;
  const float* hs  = (const float*)d_in[0];
  const float* cs  = (const float*)d_in[1];
  const float* Wq  = (const float*)d_in[2];
  const float* Wk  = (const float*)d_in[3];
  const float* Wv  = (const float*)d_in[4];
  const float* Wo  = (const float*)d_in[5];
  const float* bo  = (const float*)d_in[6];
  const float* ldw = (const float*)d_in[7];
  const float* lup = (const float*)d_in[8];
  float* out = (float*)d_out;

  const size_t MD = (size_t)4096 * 1024;   // B*S*D
  const size_t WD = (size_t)1024 * 1024;   // D*D
  __bf16* hsb = (__bf16*)d_ws;             // 4M bf16
  __bf16* Wqb = hsb + MD;                  // 1M each
  __bf16* Wkb = Wqb + WD;
  __bf16* Wvb = Wkb + WD;
  __bf16* Wob = Wvb + WD;
  __bf16* Qb  = Wob + WD;                  // 4M each
  __bf16* Kb  = Qb + MD;
  __bf16* Vb  = Kb + MD;
  __bf16* Ab  = Vb + MD;
  float*  tmp = (float*)(Ab + MD);         // [4096][4] fp32

  // 0) fp32 -> bf16 (hidden_states + 4 weights)
  cvt5_k<<<dim3(2048, 5), 256, 0, stream>>>(hs, Wq, Wk, Wv, Wo,
                                            hsb, Wqb, Wkb, Wvb, Wob);
  // 1) Q/K/V projections: M=4096, N=1024, K=1024 each
  gemm_qkv_k<<<dim3(8, 32, 3), 256, 0, stream>>>(hsb, Wqb, Wkb, Wvb, Qb, Kb, Vb);
  // 2) LoRA down (rank 4, fp32)
  lora_down_k<<<dim3(1024), 256, 0, stream>>>(cs, ldw, tmp);
  // 3) attention: 32 q-tiles x 16 (b,h)
  flash_attn_k<<<dim3(32, 16), 256, 0, stream>>>(Qb, Kb, Vb, Ab);
  // 4) output projection + bias + LoRA up (fp32 out)
  gemm_out_k<<<dim3(8, 32), 256, 0, stream>>>(Ab, Wob, bo, lup, tmp, out);
}

// Round 3
// 203.423 us; speedup vs baseline: 1.5286x; 1.5286x over previous
//
#include <hip/hip_runtime.h>
#include <hip/hip_bf16.h>

// B=2, S=2048, D=1024, H=8, HD=128, RANK=4.
// Device I/O buffers are FP32 (per reference dtypes).
// Internal pipeline: convert to bf16 in d_ws, bf16 MFMA with fp32 accum.

typedef __bf16 bf8_t __attribute__((ext_vector_type(8)));
typedef float f32x4 __attribute__((ext_vector_type(4)));

#define MFMA_BF16(a, b, c) __builtin_amdgcn_mfma_f32_16x16x32_bf16((a), (b), (c), 0, 0, 0)

__device__ __forceinline__ void gload_lds16(const void* g, void* l) {
  __builtin_amdgcn_global_load_lds(
      (const __attribute__((address_space(1))) void*)g,
      (__attribute__((address_space(3))) void*)l, 16, 0, 0);
}

// ---------------------------------------------------------------------------
// Kernel 0: fp32 -> bf16 conversion. blockIdx.y selects tensor
// (0=hidden_states 4M elems, 1..4 = Wq,Wk,Wv,Wo 1M each). 8 elems/thread.
// ---------------------------------------------------------------------------
__global__ __launch_bounds__(256) void cvt5_k(
    const float* __restrict__ s0, const float* __restrict__ s1,
    const float* __restrict__ s2, const float* __restrict__ s3,
    const float* __restrict__ s4, __bf16* __restrict__ d0,
    __bf16* __restrict__ d1, __bf16* __restrict__ d2, __bf16* __restrict__ d3,
    __bf16* __restrict__ d4) {
  const int which = blockIdx.y;
  const float* s = (which == 0) ? s0 : (which == 1) ? s1 : (which == 2) ? s2
                   : (which == 3) ? s3 : s4;
  __bf16* d = (which == 0) ? d0 : (which == 1) ? d1 : (which == 2) ? d2
              : (which == 3) ? d3 : d4;
  const int n = (which == 0) ? (4096 * 1024) : (1024 * 1024);
  const int i = (blockIdx.x * 256 + threadIdx.x) * 8;
  if (i >= n) return;
  float4 a = *(const float4*)(s + i);
  float4 b = *(const float4*)(s + i + 4);
  bf8_t r;
  r[0] = (__bf16)a.x; r[1] = (__bf16)a.y; r[2] = (__bf16)a.z; r[3] = (__bf16)a.w;
  r[4] = (__bf16)b.x; r[5] = (__bf16)b.y; r[6] = (__bf16)b.z; r[7] = (__bf16)b.w;
  *(bf8_t*)(d + i) = r;
}

// ---------------------------------------------------------------------------
// GEMM tile body: C[128,128] = A[128,K] * W[128(cols),K]^T (NT). 4 waves,
// each a 64x64 sub-tile = 4x4 fragments, BK=64. LDS linear [128][64].
// ---------------------------------------------------------------------------
__device__ __forceinline__ void gemm_tile(const __bf16* __restrict__ Abase,
                                          const __bf16* __restrict__ Wbase,
                                          int K, __bf16* sA, __bf16* sB,
                                          f32x4 acc[4][4]) {
  const int tid = threadIdx.x;
  const int wave = tid >> 6, lane = tid & 63;
  const int wr = (wave >> 1) * 64, wc = (wave & 1) * 64;
  const int lrow = lane >> 3, lchunk = lane & 7;

  for (int m = 0; m < 4; ++m)
    for (int n = 0; n < 4; ++n)
      acc[m][n] = f32x4{0.f, 0.f, 0.f, 0.f};

  for (int k0 = 0; k0 < K; k0 += 64) {
    for (int i = 0; i < 4; ++i) {
      const int rbase = i * 32 + wave * 8;
      gload_lds16(Abase + (size_t)(rbase + lrow) * K + k0 + lchunk * 8,
                  sA + rbase * 64);
      gload_lds16(Wbase + (size_t)(rbase + lrow) * K + k0 + lchunk * 8,
                  sB + rbase * 64);
    }
    __syncthreads();

    for (int kk = 0; kk < 2; ++kk) {
      bf8_t af[4], bfr[4];
      const int koff = kk * 32 + (lane >> 4) * 8;
      for (int m = 0; m < 4; ++m)
        af[m] = *(const bf8_t*)&sA[(wr + m * 16 + (lane & 15)) * 64 + koff];
      for (int n = 0; n < 4; ++n)
        bfr[n] = *(const bf8_t*)&sB[(wc + n * 16 + (lane & 15)) * 64 + koff];
      for (int m = 0; m < 4; ++m)
        for (int n = 0; n < 4; ++n)
          acc[m][n] = MFMA_BF16(af[m], bfr[n], acc[m][n]);
    }
    __syncthreads();
  }
}

// ---------------------------------------------------------------------------
// Kernel 1: QKV projections (bf16 in, bf16 out). blockIdx.z selects weight.
// ---------------------------------------------------------------------------
__global__ __launch_bounds__(256) void gemm_qkv_k(
    const __bf16* __restrict__ X, const __bf16* __restrict__ Wq,
    const __bf16* __restrict__ Wk, const __bf16* __restrict__ Wv,
    __bf16* __restrict__ Qb, __bf16* __restrict__ Kb, __bf16* __restrict__ Vb) {
  __shared__ __bf16 sA[128 * 64];
  __shared__ __bf16 sB[128 * 64];
  const int bcol = blockIdx.x, brow = blockIdx.y, z = blockIdx.z;
  const __bf16* W = (z == 0) ? Wq : (z == 1) ? Wk : Wv;
  __bf16* C = (z == 0) ? Qb : (z == 1) ? Kb : Vb;
  const int K = 1024, N = 1024;
  f32x4 acc[4][4];
  gemm_tile(X + (size_t)brow * 128 * K, W + (size_t)bcol * 128 * K, K, sA, sB, acc);

  const int lane = threadIdx.x & 63, wave = threadIdx.x >> 6;
  const int wr = (wave >> 1) * 64, wc = (wave & 1) * 64;
  const int row0 = brow * 128 + wr + (lane >> 4) * 4;
  const int col0 = bcol * 128 + wc + (lane & 15);
  for (int m = 0; m < 4; ++m)
    for (int n = 0; n < 4; ++n)
      for (int j = 0; j < 4; ++j)
        C[(size_t)(row0 + m * 16 + j) * N + col0 + n * 16] = (__bf16)acc[m][n][j];
}

// ---------------------------------------------------------------------------
// Kernel 2: LoRA down: tmp[s][r] = sum_d control[s][d]*down[r][d]. FP32 in.
// ---------------------------------------------------------------------------
__global__ __launch_bounds__(256) void lora_down_k(
    const float* __restrict__ ctrl, const float* __restrict__ down,
    float* __restrict__ tmp) {
  const int tid = threadIdx.x, wave = tid >> 6, lane = tid & 63;
  const int s = blockIdx.x * 4 + wave;
  const float* cp = ctrl + (size_t)s * 1024 + lane * 16;
  float4 c[4];
  for (int i = 0; i < 4; ++i) c[i] = *(const float4*)(cp + i * 4);
  for (int r = 0; r < 4; ++r) {
    const float* dp = down + r * 1024 + lane * 16;
    float acc = 0.f;
    for (int i = 0; i < 4; ++i) {
      float4 dv = *(const float4*)(dp + i * 4);
      acc += c[i].x * dv.x + c[i].y * dv.y + c[i].z * dv.z + c[i].w * dv.w;
    }
    for (int off = 32; off > 0; off >>= 1) acc += __shfl_xor(acc, off);
    if (lane == 0) tmp[s * 4 + r] = acc;
  }
}

// ---------------------------------------------------------------------------
// Kernel 3: flash attention (bf16 in/out, fp32 softmax+accum).
// One block per (64 q-rows, b*h); 4 waves, wave w owns 16 q-rows.
// LDS layouts (bank-conflict-free by construction):
//   sK [64][128] linear, chunk-XOR swizzled: pos(r,c) holds K[r][c^(r&7)],
//      staged via global_load_lds with pre-swizzled GLOBAL source (m173).
//   sVt[128][64] = V^T, double-XOR slot: pos(d, s, b) holds V^T[d][k] with
//      s = (k>>3)^(d&7)^((d>>3)&7), b = k&7. The (d>>3) term re-injects the
//      lane-varying index into the bank bits (else writes are 32-way).
//   sP [wave][16][72] P round-trip (2-way same-dword writes, balanced reads).
// ---------------------------------------------------------------------------
__global__ __launch_bounds__(256) void flash_attn_k(
    const __bf16* __restrict__ Qg, const __bf16* __restrict__ Kg,
    const __bf16* __restrict__ Vg, __bf16* __restrict__ Og) {
  const int S = 2048, D = 1024;
  __shared__ __bf16 sK[64 * 128];
  __shared__ __bf16 sVt[128 * 64];
  __shared__ __bf16 sP[4][16 * 72];
  const int qt = blockIdx.x, bh = blockIdx.y;
  const int b = bh >> 3, h = bh & 7;
  const int tid = threadIdx.x, wave = tid >> 6, lane = tid & 63;
  const size_t base = (size_t)b * S * D + (size_t)h * 128;
  const int q0 = qt * 64 + wave * 16;
  const int g = lane >> 4;           // 8-elem k-group within fragment
  const int koff = g * 8;

  bf8_t qf[4];
  {
    const __bf16* qp = Qg + base + (size_t)(q0 + (lane & 15)) * D + koff;
    for (int d0 = 0; d0 < 4; ++d0) qf[d0] = *(const bf8_t*)(qp + d0 * 32);
  }

  f32x4 o[8];
  for (int f = 0; f < 8; ++f) o[f] = f32x4{0.f, 0.f, 0.f, 0.f};
  float mrow[4] = {-1e30f, -1e30f, -1e30f, -1e30f};
  float lrow[4] = {0.f, 0.f, 0.f, 0.f};
  const float scale = 0.08838834764831845f;  // 1/sqrt(128)

  const int sr = tid >> 4, scnk = tid & 15;  // staging: 16 rows x 16 chunks

  for (int kv0 = 0; kv0 < S; kv0 += 64) {
    // K: async global->LDS, source chunk pre-swizzled, dest linear
    for (int i = 0; i < 4; ++i) {
      const int r = i * 16 + sr;
      const int gc = scnk ^ (r & 7);
      gload_lds16(Kg + base + (size_t)(kv0 + r) * D + gc * 8,
                  sK + i * 2048 + wave * 512);
    }
    // V: reg-staged transpose with double-XOR slot
    for (int i = 0; i < 4; ++i) {
      const int r = i * 16 + sr;
      int4 vd = *(const int4*)(Vg + base + (size_t)(kv0 + r) * D + scnk * 8);
      const __bf16* e = (const __bf16*)&vd;
      for (int j = 0; j < 8; ++j) {
        const int d = scnk * 8 + j;
        const int slot = (r >> 3) ^ (d & 7) ^ ((d >> 3) & 7);
        sVt[d * 64 + slot * 8 + (r & 7)] = e[j];
      }
    }
    __syncthreads();

    // QK^T: scores[16q][64k] as 4 col-fragments
    f32x4 s4[4];
    for (int n = 0; n < 4; ++n) {
      f32x4 a_ = f32x4{0.f, 0.f, 0.f, 0.f};
      const int r = n * 16 + (lane & 15);
      for (int d0 = 0; d0 < 4; ++d0) {
        const int c = (4 * d0 + g) ^ (r & 7);
        a_ = MFMA_BF16(qf[d0], *(const bf8_t*)&sK[r * 128 + c * 8], a_);
      }
      s4[n] = a_;
    }
    for (int n = 0; n < 4; ++n) s4[n] = s4[n] * scale;

    // online softmax; register j <-> q-row (lane>>4)*4+j
    float tmax[4];
    for (int j = 0; j < 4; ++j)
      tmax[j] = fmaxf(fmaxf(s4[0][j], s4[1][j]), fmaxf(s4[2][j], s4[3][j]));
    for (int off = 1; off < 16; off <<= 1)
      for (int j = 0; j < 4; ++j)
        tmax[j] = fmaxf(tmax[j], __shfl_xor(tmax[j], off));
    float sc_[4], rs[4];
    for (int j = 0; j < 4; ++j) {
      float mnew = fmaxf(mrow[j], tmax[j]);
      sc_[j] = __expf(mrow[j] - mnew);
      mrow[j] = mnew;
      rs[j] = 0.f;
    }
    for (int n = 0; n < 4; ++n)
      for (int j = 0; j < 4; ++j) {
        float p = __expf(s4[n][j] - mrow[j]);
        s4[n][j] = p;
        rs[j] += p;
      }
    for (int off = 1; off < 16; off <<= 1)
      for (int j = 0; j < 4; ++j) rs[j] += __shfl_xor(rs[j], off);
    for (int j = 0; j < 4; ++j) lrow[j] = lrow[j] * sc_[j] + rs[j];
    for (int f = 0; f < 8; ++f)
      for (int j = 0; j < 4; ++j) o[f][j] *= sc_[j];

    // P -> per-wave LDS (D-layout in, A-layout out)
    __bf16* pw = &sP[wave][0];
    for (int n = 0; n < 4; ++n)
      for (int j = 0; j < 4; ++j)
        pw[(g * 4 + j) * 72 + n * 16 + (lane & 15)] = (__bf16)s4[n][j];

    // PV: O[16q][128d] += P[16q][64kv] * V[64kv][128d]
    for (int kk = 0; kk < 2; ++kk) {
      bf8_t pa = *(const bf8_t*)&pw[(lane & 15) * 72 + kk * 32 + koff];
      for (int f = 0; f < 8; ++f) {
        const int d = f * 16 + (lane & 15);
        const int slot = (4 * kk + g) ^ (d & 7) ^ ((d >> 3) & 7);
        bf8_t vb = *(const bf8_t*)&sVt[d * 64 + slot * 8];
        o[f] = MFMA_BF16(pa, vb, o[f]);
      }
    }
    __syncthreads();
  }

  float inv[4];
  for (int j = 0; j < 4; ++j) inv[j] = 1.f / lrow[j];
  for (int f = 0; f < 8; ++f)
    for (int j = 0; j < 4; ++j)
      Og[base + (size_t)(q0 + g * 4 + j) * D + f * 16 + (lane & 15)] =
          (__bf16)(o[f][j] * inv[j]);
}

// ---------------------------------------------------------------------------
// Kernel 4: output projection + bias + LoRA-up. bf16 GEMM, fp32 epilogue/out.
// ---------------------------------------------------------------------------
__global__ __launch_bounds__(256) void gemm_out_k(
    const __bf16* __restrict__ A, const __bf16* __restrict__ Wo,
    const float* __restrict__ bo, const float* __restrict__ lup,
    const float* __restrict__ tmp, float* __restrict__ out) {
  __shared__ __bf16 sA[128 * 64];
  __shared__ __bf16 sB[128 * 64];
  const int bcol = blockIdx.x, brow = blockIdx.y;
  const int K = 1024, N = 1024;
  f32x4 acc[4][4];
  gemm_tile(A + (size_t)brow * 128 * K, Wo + (size_t)bcol * 128 * K, K, sA, sB, acc);

  const int lane = threadIdx.x & 63, wave = threadIdx.x >> 6;
  const int wr = (wave >> 1) * 64, wc = (wave & 1) * 64;
  for (int n = 0; n < 4; ++n) {
    const int col = bcol * 128 + wc + n * 16 + (lane & 15);
    const float bias = bo[col];
    const float u0 = lup[col * 4 + 0], u1 = lup[col * 4 + 1];
    const float u2 = lup[col * 4 + 2], u3 = lup[col * 4 + 3];
    for (int m = 0; m < 4; ++m)
      for (int j = 0; j < 4; ++j) {
        const int row = brow * 128 + wr + m * 16 + (lane >> 4) * 4 + j;
        const float* t = tmp + row * 4;
        float v = acc[m][n][j] + bias + t[0] * u0 + t[1] * u1 + t[2] * u2 + t[3] * u3;
        out[(size_t)row * N + col] = v;
      }
  }
}

// ---------------------------------------------------------------------------
extern "C" void kernel_launch(void* const* d_in, const int* in_sizes, int n_in,
                              void* d_out, int out_size, void* d_ws, size_t ws_size,
                              hipStream_t stream) {
  (void)in_sizes; (void)n_in; (void)out_size; (void)ws_size;
  const float* hs  = (const float*)d_in[0];
  const float* cs  = (const float*)d_in[1];
  const float* Wq  = (const float*)d_in[2];
  const float* Wk  = (const float*)d_in[3];
  const float* Wv  = (const float*)d_in[4];
  const float* Wo  = (const float*)d_in[5];
  const float* bo  = (const float*)d_in[6];
  const float* ldw = (const float*)d_in[7];
  const float* lup = (const float*)d_in[8];
  float* out = (float*)d_out;

  const size_t MD = (size_t)4096 * 1024;   // B*S*D
  const size_t WD = (size_t)1024 * 1024;   // D*D
  __bf16* hsb = (__bf16*)d_ws;
  __bf16* Wqb = hsb + MD;
  __bf16* Wkb = Wqb + WD;
  __bf16* Wvb = Wkb + WD;
  __bf16* Wob = Wvb + WD;
  __bf16* Qb  = Wob + WD;
  __bf16* Kb  = Qb + MD;
  __bf16* Vb  = Kb + MD;
  __bf16* Ab  = Vb + MD;
  float*  tmp = (float*)(Ab + MD);

  cvt5_k<<<dim3(2048, 5), 256, 0, stream>>>(hs, Wq, Wk, Wv, Wo,
                                            hsb, Wqb, Wkb, Wvb, Wob);
  gemm_qkv_k<<<dim3(8, 32, 3), 256, 0, stream>>>(hsb, Wqb, Wkb, Wvb, Qb, Kb, Vb);
  lora_down_k<<<dim3(1024), 256, 0, stream>>>(cs, ldw, tmp);
  flash_attn_k<<<dim3(32, 16), 256, 0, stream>>>(Qb, Kb, Vb, Ab);
  gemm_out_k<<<dim3(8, 32), 256, 0, stream>>>(Ab, Wob, bo, lup, tmp, out);
}

// Round 4
// 190.639 us; speedup vs baseline: 1.6311x; 1.0671x over previous
//
#include <hip/hip_runtime.h>
#include <hip/hip_bf16.h>

// B=2, S=2048, D=1024, H=8, HD=128, RANK=4.
// Device I/O buffers are FP32 (per reference dtypes).
// Internal pipeline: convert to bf16 in d_ws, bf16 MFMA with fp32 accum.
// V is produced TRANSPOSED by the QKV GEMM (operand swap), so flash attention
// stages both K and V^T with global_load_lds + XOR-swizzled source (m173).

typedef __bf16 bf8_t __attribute__((ext_vector_type(8)));
typedef float f32x4 __attribute__((ext_vector_type(4)));

#define MFMA_BF16(a, b, c) __builtin_amdgcn_mfma_f32_16x16x32_bf16((a), (b), (c), 0, 0, 0)

__device__ __forceinline__ void gload_lds16(const void* g, void* l) {
  __builtin_amdgcn_global_load_lds(
      (const __attribute__((address_space(1))) void*)g,
      (__attribute__((address_space(3))) void*)l, 16, 0, 0);
}

// ---------------------------------------------------------------------------
// Kernel 0: fp32 -> bf16 conversion. blockIdx.y selects tensor
// (0=hidden_states 4M elems, 1..4 = Wq,Wk,Wv,Wo 1M each). 8 elems/thread.
// ---------------------------------------------------------------------------
__global__ __launch_bounds__(256) void cvt5_k(
    const float* __restrict__ s0, const float* __restrict__ s1,
    const float* __restrict__ s2, const float* __restrict__ s3,
    const float* __restrict__ s4, __bf16* __restrict__ d0,
    __bf16* __restrict__ d1, __bf16* __restrict__ d2, __bf16* __restrict__ d3,
    __bf16* __restrict__ d4) {
  const int which = blockIdx.y;
  const float* s = (which == 0) ? s0 : (which == 1) ? s1 : (which == 2) ? s2
                   : (which == 3) ? s3 : s4;
  __bf16* d = (which == 0) ? d0 : (which == 1) ? d1 : (which == 2) ? d2
              : (which == 3) ? d3 : d4;
  const int n = (which == 0) ? (4096 * 1024) : (1024 * 1024);
  const int i = (blockIdx.x * 256 + threadIdx.x) * 8;
  if (i >= n) return;
  float4 a = *(const float4*)(s + i);
  float4 b = *(const float4*)(s + i + 4);
  bf8_t r;
  r[0] = (__bf16)a.x; r[1] = (__bf16)a.y; r[2] = (__bf16)a.z; r[3] = (__bf16)a.w;
  r[4] = (__bf16)b.x; r[5] = (__bf16)b.y; r[6] = (__bf16)b.z; r[7] = (__bf16)b.w;
  *(bf8_t*)(d + i) = r;
}

// ---------------------------------------------------------------------------
// GEMM tile body: C[128,128] = A[128,K] * W[128(cols),K]^T (NT). 4 waves,
// each a 64x64 sub-tile = 4x4 fragments, BK=64. LDS linear [128][64].
// ---------------------------------------------------------------------------
__device__ __forceinline__ void gemm_tile(const __bf16* __restrict__ Abase,
                                          const __bf16* __restrict__ Wbase,
                                          int K, __bf16* sA, __bf16* sB,
                                          f32x4 acc[4][4]) {
  const int tid = threadIdx.x;
  const int wave = tid >> 6, lane = tid & 63;
  const int wr = (wave >> 1) * 64, wc = (wave & 1) * 64;
  const int lrow = lane >> 3, lchunk = lane & 7;

  for (int m = 0; m < 4; ++m)
    for (int n = 0; n < 4; ++n)
      acc[m][n] = f32x4{0.f, 0.f, 0.f, 0.f};

  for (int k0 = 0; k0 < K; k0 += 64) {
    for (int i = 0; i < 4; ++i) {
      const int rbase = i * 32 + wave * 8;
      gload_lds16(Abase + (size_t)(rbase + lrow) * K + k0 + lchunk * 8,
                  sA + rbase * 64);
      gload_lds16(Wbase + (size_t)(rbase + lrow) * K + k0 + lchunk * 8,
                  sB + rbase * 64);
    }
    __syncthreads();

    for (int kk = 0; kk < 2; ++kk) {
      bf8_t af[4], bfr[4];
      const int koff = kk * 32 + (lane >> 4) * 8;
      for (int m = 0; m < 4; ++m)
        af[m] = *(const bf8_t*)&sA[(wr + m * 16 + (lane & 15)) * 64 + koff];
      for (int n = 0; n < 4; ++n)
        bfr[n] = *(const bf8_t*)&sB[(wc + n * 16 + (lane & 15)) * 64 + koff];
      for (int m = 0; m < 4; ++m)
        for (int n = 0; n < 4; ++n)
          acc[m][n] = MFMA_BF16(af[m], bfr[n], acc[m][n]);
    }
    __syncthreads();
  }
}

// ---------------------------------------------------------------------------
// Kernel 1: QKV projections (bf16 in, bf16 out). blockIdx.z selects weight.
// z==0/1: C[s][e] = X[s][:].W[e][:]    (4096x1024), row/col tiles = (y,x)
// z==2:   OPERANDS SWAPPED: Ct[e][s] = Wv[e][:].X[s][:]  (1024x4096)
//         -> output IS V^T per (h,b): Vt[h*128+d][b*2048+s], row/col = (x,y)
// ---------------------------------------------------------------------------
__global__ __launch_bounds__(256) void gemm_qkv_k(
    const __bf16* __restrict__ X, const __bf16* __restrict__ Wq,
    const __bf16* __restrict__ Wk, const __bf16* __restrict__ Wv,
    __bf16* __restrict__ Qb, __bf16* __restrict__ Kb, __bf16* __restrict__ Vtb) {
  __shared__ __bf16 sA[128 * 64];
  __shared__ __bf16 sB[128 * 64];
  const int z = blockIdx.z;
  const int K = 1024;
  int rowT, colT, Nout;
  const __bf16 *Abase, *Wbase;
  __bf16* C;
  if (z == 2) {
    rowT = blockIdx.x; colT = blockIdx.y; Nout = 4096;
    Abase = Wv + (size_t)rowT * 128 * K;
    Wbase = X + (size_t)colT * 128 * K;
    C = Vtb;
  } else {
    rowT = blockIdx.y; colT = blockIdx.x; Nout = 1024;
    Abase = X + (size_t)rowT * 128 * K;
    Wbase = ((z == 0) ? Wq : Wk) + (size_t)colT * 128 * K;
    C = (z == 0) ? Qb : Kb;
  }
  f32x4 acc[4][4];
  gemm_tile(Abase, Wbase, K, sA, sB, acc);

  const int lane = threadIdx.x & 63, wave = threadIdx.x >> 6;
  const int wr = (wave >> 1) * 64, wc = (wave & 1) * 64;
  const int row0 = rowT * 128 + wr + (lane >> 4) * 4;
  const int col0 = colT * 128 + wc + (lane & 15);
  for (int m = 0; m < 4; ++m)
    for (int n = 0; n < 4; ++n)
      for (int j = 0; j < 4; ++j)
        C[(size_t)(row0 + m * 16 + j) * Nout + col0 + n * 16] = (__bf16)acc[m][n][j];
}

// ---------------------------------------------------------------------------
// Kernel 2: LoRA down: tmp[s][r] = sum_d control[s][d]*down[r][d]. FP32 in.
// ---------------------------------------------------------------------------
__global__ __launch_bounds__(256) void lora_down_k(
    const float* __restrict__ ctrl, const float* __restrict__ down,
    float* __restrict__ tmp) {
  const int tid = threadIdx.x, wave = tid >> 6, lane = tid & 63;
  const int s = blockIdx.x * 4 + wave;
  const float* cp = ctrl + (size_t)s * 1024 + lane * 16;
  float4 c[4];
  for (int i = 0; i < 4; ++i) c[i] = *(const float4*)(cp + i * 4);
  for (int r = 0; r < 4; ++r) {
    const float* dp = down + r * 1024 + lane * 16;
    float acc = 0.f;
    for (int i = 0; i < 4; ++i) {
      float4 dv = *(const float4*)(dp + i * 4);
      acc += c[i].x * dv.x + c[i].y * dv.y + c[i].z * dv.z + c[i].w * dv.w;
    }
    for (int off = 32; off > 0; off >>= 1) acc += __shfl_xor(acc, off);
    if (lane == 0) tmp[s * 4 + r] = acc;
  }
}

// ---------------------------------------------------------------------------
// Kernel 3: flash attention (bf16 in/out, fp32 softmax+accum).
// One block per (64 q-rows, b*h); 4 waves, wave w owns 16 q-rows.
// K  [2][64][128]  double-buffered, XOR-swizzled src, DMA-staged.
// Vt [2][128][64]  double-buffered, XOR-swizzled src, DMA-staged (V already
//                  transposed in global: Vt[h*128+d][b*2048+s]).
// sP [4][16][72]   P round-trip (per-wave).
// ONE barrier per tile: sync -> issue next-tile DMA -> compute current; the
// DMA drains at the NEXT barrier, so staging overlaps compute (T3 minimum).
// ---------------------------------------------------------------------------
__global__ __launch_bounds__(256) void flash_attn_k(
    const __bf16* __restrict__ Qg, const __bf16* __restrict__ Kg,
    const __bf16* __restrict__ Vtg, __bf16* __restrict__ Og) {
  const int S = 2048, D = 1024;
  __shared__ __bf16 sK[2][64 * 128];
  __shared__ __bf16 sVt[2][128 * 64];
  __shared__ __bf16 sP[4][16 * 72];
  const int qt = blockIdx.x, bh = blockIdx.y;
  const int b = bh >> 3, h = bh & 7;
  const int tid = threadIdx.x, wave = tid >> 6, lane = tid & 63;
  const size_t base = (size_t)b * S * D + (size_t)h * 128;
  const size_t vtbase = (size_t)h * 128 * 4096 + (size_t)b * 2048;
  const int q0 = qt * 64 + wave * 16;
  const int g = lane >> 4;  // 8-elem k-group within fragment
  const int koff = g * 8;

  // Q fragments, pre-scaled by 1/sqrt(128)
  bf8_t qf[4];
  {
    const float scale = 0.08838834764831845f;
    const __bf16* qp = Qg + base + (size_t)(q0 + (lane & 15)) * D + koff;
    for (int d0 = 0; d0 < 4; ++d0) {
      bf8_t v = *(const bf8_t*)(qp + d0 * 32);
      for (int j = 0; j < 8; ++j) v[j] = (__bf16)((float)v[j] * scale);
      qf[d0] = v;
    }
  }

  f32x4 o[8];
  for (int f = 0; f < 8; ++f) o[f] = f32x4{0.f, 0.f, 0.f, 0.f};
  float mrow[4] = {-1e30f, -1e30f, -1e30f, -1e30f};
  float lrow[4] = {0.f, 0.f, 0.f, 0.f};

  // staging (per wave: 4 issues K, 4 issues Vt; 1 KiB each)
  auto stageK = [&](int buf, int kv) {
    for (int i = 0; i < 4; ++i) {
      const int r = i * 16 + wave * 4 + (lane >> 4);
      const int gc = (lane & 15) ^ (r & 7);
      gload_lds16(Kg + base + (size_t)(kv + r) * D + gc * 8,
                  &sK[buf][i * 2048 + wave * 512]);
    }
  };
  auto stageV = [&](int buf, int kv) {
    for (int i = 0; i < 4; ++i) {
      const int r = wave * 32 + i * 8 + (lane >> 3);  // d-row
      const int gc = (lane & 7) ^ (r & 7);
      gload_lds16(Vtg + vtbase + (size_t)r * 4096 + kv + gc * 8,
                  &sVt[buf][(wave * 32 + i * 8) * 64]);
    }
  };

  stageK(0, 0);
  stageV(0, 0);

  for (int t = 0; t < 32; ++t) {
    const int cur = t & 1;
    __syncthreads();  // drains my DMA (incl. buf[cur]); all waves past reads of buf[cur^1]
    if (t < 31) {
      stageK(cur ^ 1, (t + 1) * 64);
      stageV(cur ^ 1, (t + 1) * 64);
    }

    // QK^T: scores[16q][64k] as 4 col-fragments (Q pre-scaled)
    f32x4 s4[4];
    const __bf16* kb_ = sK[cur];
    for (int n = 0; n < 4; ++n) {
      f32x4 a_ = f32x4{0.f, 0.f, 0.f, 0.f};
      const int r = n * 16 + (lane & 15);
      for (int d0 = 0; d0 < 4; ++d0) {
        const int c = (4 * d0 + g) ^ (r & 7);
        a_ = MFMA_BF16(qf[d0], *(const bf8_t*)&kb_[r * 128 + c * 8], a_);
      }
      s4[n] = a_;
    }

    // online softmax; register j <-> q-row g*4+j
    float tmax[4];
    for (int j = 0; j < 4; ++j)
      tmax[j] = fmaxf(fmaxf(s4[0][j], s4[1][j]), fmaxf(s4[2][j], s4[3][j]));
    for (int off = 1; off < 16; off <<= 1)
      for (int j = 0; j < 4; ++j)
        tmax[j] = fmaxf(tmax[j], __shfl_xor(tmax[j], off));
    float sc_[4], rs[4];
    for (int j = 0; j < 4; ++j) {
      float mnew = fmaxf(mrow[j], tmax[j]);
      sc_[j] = __expf(mrow[j] - mnew);
      mrow[j] = mnew;
      rs[j] = 0.f;
    }
    for (int n = 0; n < 4; ++n)
      for (int j = 0; j < 4; ++j) {
        float p = __expf(s4[n][j] - mrow[j]);
        s4[n][j] = p;
        rs[j] += p;
      }
    for (int off = 1; off < 16; off <<= 1)
      for (int j = 0; j < 4; ++j) rs[j] += __shfl_xor(rs[j], off);
    for (int j = 0; j < 4; ++j) lrow[j] = lrow[j] * sc_[j] + rs[j];
    for (int f = 0; f < 8; ++f)
      for (int j = 0; j < 4; ++j) o[f][j] *= sc_[j];

    // P -> per-wave LDS (D-layout in, A-layout out; same-wave ordering)
    __bf16* pw = &sP[wave][0];
    for (int n = 0; n < 4; ++n)
      for (int j = 0; j < 4; ++j)
        pw[(g * 4 + j) * 72 + n * 16 + (lane & 15)] = (__bf16)s4[n][j];

    // PV: O[16q][128d] += P[16q][64kv] * V[64kv][128d]
    const __bf16* vt_ = sVt[cur];
    for (int kk = 0; kk < 2; ++kk) {
      bf8_t pa = *(const bf8_t*)&pw[(lane & 15) * 72 + kk * 32 + koff];
      for (int f = 0; f < 8; ++f) {
        const int d = f * 16 + (lane & 15);
        const int c = (4 * kk + g) ^ (d & 7);
        bf8_t vb = *(const bf8_t*)&vt_[d * 64 + c * 8];
        o[f] = MFMA_BF16(pa, vb, o[f]);
      }
    }
  }

  float inv[4];
  for (int j = 0; j < 4; ++j) inv[j] = 1.f / lrow[j];
  for (int f = 0; f < 8; ++f)
    for (int j = 0; j < 4; ++j)
      Og[base + (size_t)(q0 + g * 4 + j) * D + f * 16 + (lane & 15)] =
          (__bf16)(o[f][j] * inv[j]);
}

// ---------------------------------------------------------------------------
// Kernel 4: output projection + bias + LoRA-up. bf16 GEMM, fp32 epilogue/out.
// ---------------------------------------------------------------------------
__global__ __launch_bounds__(256) void gemm_out_k(
    const __bf16* __restrict__ A, const __bf16* __restrict__ Wo,
    const float* __restrict__ bo, const float* __restrict__ lup,
    const float* __restrict__ tmp, float* __restrict__ out) {
  __shared__ __bf16 sA[128 * 64];
  __shared__ __bf16 sB[128 * 64];
  const int bcol = blockIdx.x, brow = blockIdx.y;
  const int K = 1024, N = 1024;
  f32x4 acc[4][4];
  gemm_tile(A + (size_t)brow * 128 * K, Wo + (size_t)bcol * 128 * K, K, sA, sB, acc);

  const int lane = threadIdx.x & 63, wave = threadIdx.x >> 6;
  const int wr = (wave >> 1) * 64, wc = (wave & 1) * 64;
  for (int n = 0; n < 4; ++n) {
    const int col = bcol * 128 + wc + n * 16 + (lane & 15);
    const float bias = bo[col];
    const float u0 = lup[col * 4 + 0], u1 = lup[col * 4 + 1];
    const float u2 = lup[col * 4 + 2], u3 = lup[col * 4 + 3];
    for (int m = 0; m < 4; ++m)
      for (int j = 0; j < 4; ++j) {
        const int row = brow * 128 + wr + m * 16 + (lane >> 4) * 4 + j;
        const float* t = tmp + row * 4;
        float v = acc[m][n][j] + bias + t[0] * u0 + t[1] * u1 + t[2] * u2 + t[3] * u3;
        out[(size_t)row * N + col] = v;
      }
  }
}

// ---------------------------------------------------------------------------
extern "C" void kernel_launch(void* const* d_in, const int* in_sizes, int n_in,
                              void* d_out, int out_size, void* d_ws, size_t ws_size,
                              hipStream_t stream) {
  (void)in_sizes; (void)n_in; (void)out_size; (void)ws_size;
  const float* hs  = (const float*)d_in[0];
  const float* cs  = (const float*)d_in[1];
  const float* Wq  = (const float*)d_in[2];
  const float* Wk  = (const float*)d_in[3];
  const float* Wv  = (const float*)d_in[4];
  const float* Wo  = (const float*)d_in[5];
  const float* bo  = (const float*)d_in[6];
  const float* ldw = (const float*)d_in[7];
  const float* lup = (const float*)d_in[8];
  float* out = (float*)d_out;

  const size_t MD = (size_t)4096 * 1024;   // B*S*D
  const size_t WD = (size_t)1024 * 1024;   // D*D
  __bf16* hsb = (__bf16*)d_ws;
  __bf16* Wqb = hsb + MD;
  __bf16* Wkb = Wqb + WD;
  __bf16* Wvb = Wkb + WD;
  __bf16* Wob = Wvb + WD;
  __bf16* Qb  = Wob + WD;
  __bf16* Kb  = Qb + MD;
  __bf16* Vtb = Kb + MD;   // V^T: [h*128+d][b*2048+s] = [1024][4096]
  __bf16* Ab  = Vtb + MD;
  float*  tmp = (float*)(Ab + MD);

  cvt5_k<<<dim3(2048, 5), 256, 0, stream>>>(hs, Wq, Wk, Wv, Wo,
                                            hsb, Wqb, Wkb, Wvb, Wob);
  gemm_qkv_k<<<dim3(8, 32, 3), 256, 0, stream>>>(hsb, Wqb, Wkb, Wvb, Qb, Kb, Vtb);
  lora_down_k<<<dim3(1024), 256, 0, stream>>>(cs, ldw, tmp);
  flash_attn_k<<<dim3(32, 16), 256, 0, stream>>>(Qb, Kb, Vtb, Ab);
  gemm_out_k<<<dim3(8, 32), 256, 0, stream>>>(Ab, Wob, bo, lup, tmp, out);
}

// Round 5
// 176.000 us; speedup vs baseline: 1.7668x; 1.0832x over previous
//
#include <hip/hip_runtime.h>
#include <hip/hip_bf16.h>

// B=2, S=2048, D=1024, H=8, HD=128, RANK=4.
// Device I/O buffers are FP32 (per reference dtypes).
// Internal pipeline: convert to bf16 in d_ws, bf16 MFMA with fp32 accum.
// V is produced TRANSPOSED by the QKV GEMM (operand swap). Flash attention
// uses swapped QK^T (mfma(K,Q)) with 32x32x16 MFMA so softmax is fully
// in-register (m214 structure): row-reduce = in-reg tree + 1 shfl_xor(32);
// P reaches the PV A-fragment via 8 packed-u32 lane-pair exchanges.

typedef __bf16 bf8_t __attribute__((ext_vector_type(8)));
typedef float f32x4 __attribute__((ext_vector_type(4)));
typedef float f32x16 __attribute__((ext_vector_type(16)));
typedef unsigned u32x4 __attribute__((ext_vector_type(4)));

#define MFMA16(a, b, c) __builtin_amdgcn_mfma_f32_16x16x32_bf16((a), (b), (c), 0, 0, 0)
#define MFMA32(a, b, c) __builtin_amdgcn_mfma_f32_32x32x16_bf16((a), (b), (c), 0, 0, 0)

__device__ __forceinline__ void gload_lds16(const void* g, void* l) {
  __builtin_amdgcn_global_load_lds(
      (const __attribute__((address_space(1))) void*)g,
      (__attribute__((address_space(3))) void*)l, 16, 0, 0);
}

__device__ __forceinline__ unsigned pk2(float a, float b) {
  unsigned short ua = __builtin_bit_cast(unsigned short, (__bf16)a);
  unsigned short ub = __builtin_bit_cast(unsigned short, (__bf16)b);
  return (unsigned)ua | ((unsigned)ub << 16);
}

// ---------------------------------------------------------------------------
// Kernel 0: fp32 -> bf16 conversion (hidden_states + Wq,Wk,Wv,Wo).
// ---------------------------------------------------------------------------
__global__ __launch_bounds__(256) void cvt5_k(
    const float* __restrict__ s0, const float* __restrict__ s1,
    const float* __restrict__ s2, const float* __restrict__ s3,
    const float* __restrict__ s4, __bf16* __restrict__ d0,
    __bf16* __restrict__ d1, __bf16* __restrict__ d2, __bf16* __restrict__ d3,
    __bf16* __restrict__ d4) {
  const int which = blockIdx.y;
  const float* s = (which == 0) ? s0 : (which == 1) ? s1 : (which == 2) ? s2
                   : (which == 3) ? s3 : s4;
  __bf16* d = (which == 0) ? d0 : (which == 1) ? d1 : (which == 2) ? d2
              : (which == 3) ? d3 : d4;
  const int n = (which == 0) ? (4096 * 1024) : (1024 * 1024);
  const int i = (blockIdx.x * 256 + threadIdx.x) * 8;
  if (i >= n) return;
  float4 a = *(const float4*)(s + i);
  float4 b = *(const float4*)(s + i + 4);
  bf8_t r;
  r[0] = (__bf16)a.x; r[1] = (__bf16)a.y; r[2] = (__bf16)a.z; r[3] = (__bf16)a.w;
  r[4] = (__bf16)b.x; r[5] = (__bf16)b.y; r[6] = (__bf16)b.z; r[7] = (__bf16)b.w;
  *(bf8_t*)(d + i) = r;
}

// ---------------------------------------------------------------------------
// GEMM tile body: C[128,128] = A[128,K] * W[128(cols),K]^T (NT). 4 waves,
// each a 64x64 sub-tile = 4x4 fragments of 16x16, BK=64. LDS linear [128][64].
// ---------------------------------------------------------------------------
__device__ __forceinline__ void gemm_tile(const __bf16* __restrict__ Abase,
                                          const __bf16* __restrict__ Wbase,
                                          int K, __bf16* sA, __bf16* sB,
                                          f32x4 acc[4][4]) {
  const int tid = threadIdx.x;
  const int wave = tid >> 6, lane = tid & 63;
  const int wr = (wave >> 1) * 64, wc = (wave & 1) * 64;
  const int lrow = lane >> 3, lchunk = lane & 7;

  for (int m = 0; m < 4; ++m)
    for (int n = 0; n < 4; ++n)
      acc[m][n] = f32x4{0.f, 0.f, 0.f, 0.f};

  for (int k0 = 0; k0 < K; k0 += 64) {
    for (int i = 0; i < 4; ++i) {
      const int rbase = i * 32 + wave * 8;
      gload_lds16(Abase + (size_t)(rbase + lrow) * K + k0 + lchunk * 8,
                  sA + rbase * 64);
      gload_lds16(Wbase + (size_t)(rbase + lrow) * K + k0 + lchunk * 8,
                  sB + rbase * 64);
    }
    __syncthreads();

    for (int kk = 0; kk < 2; ++kk) {
      bf8_t af[4], bfr[4];
      const int koff = kk * 32 + (lane >> 4) * 8;
      for (int m = 0; m < 4; ++m)
        af[m] = *(const bf8_t*)&sA[(wr + m * 16 + (lane & 15)) * 64 + koff];
      for (int n = 0; n < 4; ++n)
        bfr[n] = *(const bf8_t*)&sB[(wc + n * 16 + (lane & 15)) * 64 + koff];
      for (int m = 0; m < 4; ++m)
        for (int n = 0; n < 4; ++n)
          acc[m][n] = MFMA16(af[m], bfr[n], acc[m][n]);
    }
    __syncthreads();
  }
}

// ---------------------------------------------------------------------------
// Kernel 1: QKV projections. z==0/1: C = X.W^T; z==2: operands swapped so the
// output IS V^T: Vt[h*128+d][b*2048+s] (row-major [1024][4096]).
// ---------------------------------------------------------------------------
__global__ __launch_bounds__(256) void gemm_qkv_k(
    const __bf16* __restrict__ X, const __bf16* __restrict__ Wq,
    const __bf16* __restrict__ Wk, const __bf16* __restrict__ Wv,
    __bf16* __restrict__ Qb, __bf16* __restrict__ Kb, __bf16* __restrict__ Vtb) {
  __shared__ __bf16 sA[128 * 64];
  __shared__ __bf16 sB[128 * 64];
  const int z = blockIdx.z;
  const int K = 1024;
  int rowT, colT, Nout;
  const __bf16 *Abase, *Wbase;
  __bf16* C;
  if (z == 2) {
    rowT = blockIdx.x; colT = blockIdx.y; Nout = 4096;
    Abase = Wv + (size_t)rowT * 128 * K;
    Wbase = X + (size_t)colT * 128 * K;
    C = Vtb;
  } else {
    rowT = blockIdx.y; colT = blockIdx.x; Nout = 1024;
    Abase = X + (size_t)rowT * 128 * K;
    Wbase = ((z == 0) ? Wq : Wk) + (size_t)colT * 128 * K;
    C = (z == 0) ? Qb : Kb;
  }
  f32x4 acc[4][4];
  gemm_tile(Abase, Wbase, K, sA, sB, acc);

  const int lane = threadIdx.x & 63, wave = threadIdx.x >> 6;
  const int wr = (wave >> 1) * 64, wc = (wave & 1) * 64;
  const int row0 = rowT * 128 + wr + (lane >> 4) * 4;
  const int col0 = colT * 128 + wc + (lane & 15);
  for (int m = 0; m < 4; ++m)
    for (int n = 0; n < 4; ++n)
      for (int j = 0; j < 4; ++j)
        C[(size_t)(row0 + m * 16 + j) * Nout + col0 + n * 16] = (__bf16)acc[m][n][j];
}

// ---------------------------------------------------------------------------
// Kernel 2: LoRA down: tmp[s][r] = sum_d control[s][d]*down[r][d]. FP32 in.
// ---------------------------------------------------------------------------
__global__ __launch_bounds__(256) void lora_down_k(
    const float* __restrict__ ctrl, const float* __restrict__ down,
    float* __restrict__ tmp) {
  const int tid = threadIdx.x, wave = tid >> 6, lane = tid & 63;
  const int s = blockIdx.x * 4 + wave;
  const float* cp = ctrl + (size_t)s * 1024 + lane * 16;
  float4 c[4];
  for (int i = 0; i < 4; ++i) c[i] = *(const float4*)(cp + i * 4);
  for (int r = 0; r < 4; ++r) {
    const float* dp = down + r * 1024 + lane * 16;
    float acc = 0.f;
    for (int i = 0; i < 4; ++i) {
      float4 dv = *(const float4*)(dp + i * 4);
      acc += c[i].x * dv.x + c[i].y * dv.y + c[i].z * dv.z + c[i].w * dv.w;
    }
    for (int off = 32; off > 0; off >>= 1) acc += __shfl_xor(acc, off);
    if (lane == 0) tmp[s * 4 + r] = acc;
  }
}

// ---------------------------------------------------------------------------
// Kernel 3: flash attention, swapped-QK^T 32x32 structure.
// 128 threads = 2 waves; wave owns 32 q-rows (QBLK=64/block); KVBLK=64.
// grid (32 q-tiles, 16 bh) = 512 blocks = 2 blocks/CU (LDS 64.3 KB).
//   sK [2][64][128]  dbuf, chunk-XOR swizzle (pos(r,c) holds K[r][c^(r&7)])
//   sVt[2][128][64]  dbuf, same swizzle on k-chunks
//   sW [2][32]       per-wave f32 broadcast scratch (rescale / final 1/l)
// Per tile: barrier -> issue next-tile DMA -> QK^T (lane owns q=lane&31 row)
// -> in-reg softmax (tree + shfl_xor32; defer-max THR=8, log2 domain)
// -> pack P to bf16, 8 u32 lane-pair exchanges -> PV.
// ---------------------------------------------------------------------------
__global__ __launch_bounds__(128) void flash_attn_k(
    const __bf16* __restrict__ Qg, const __bf16* __restrict__ Kg,
    const __bf16* __restrict__ Vtg, __bf16* __restrict__ Og) {
  const int S = 2048, D = 1024;
  __shared__ __bf16 sK[2][64 * 128];
  __shared__ __bf16 sVt[2][128 * 64];
  __shared__ float sW[2][32];
  const int qt = blockIdx.x, bh = blockIdx.y;
  const int b = bh >> 3, h = bh & 7;
  const int tid = threadIdx.x, wave = tid >> 6, lane = tid & 63;
  const int l31 = lane & 31, hi = lane >> 5;
  const size_t base = (size_t)b * S * D + (size_t)h * 128;
  const size_t vtbase = (size_t)h * 128 * 4096 + (size_t)b * 2048;
  const int q0 = qt * 64 + wave * 32;

  // Q as B-fragments (B[kd][q]: q=lane&31, kd=8*hi+j), pre-scaled by
  // (1/sqrt(128))*log2(e) so softmax runs in exp2 domain.
  bf8_t qf[8];
  {
    const float c = 0.08838834764831845f * 1.4426950408889634f;
    const __bf16* qp = Qg + base + (size_t)(q0 + l31) * D + hi * 8;
#pragma unroll
    for (int dc = 0; dc < 8; ++dc) {
      bf8_t v = *(const bf8_t*)(qp + dc * 16);
#pragma unroll
      for (int j = 0; j < 8; ++j) v[j] = (__bf16)((float)v[j] * c);
      qf[dc] = v;
    }
  }

  f32x16 accO[4];
#pragma unroll
  for (int db = 0; db < 4; ++db)
#pragma unroll
    for (int j = 0; j < 16; ++j) accO[db][j] = 0.f;
  float m_ = -1e30f, l_ = 0.f;

  auto stageK = [&](int buf, int kv) {
#pragma unroll
    for (int i = 0; i < 8; ++i) {
      const int r = wave * 32 + i * 4 + (lane >> 4);
      const int gc = (lane & 15) ^ (r & 7);
      gload_lds16(Kg + base + (size_t)(kv + r) * D + gc * 8,
                  &sK[buf][(wave * 32 + i * 4) * 128]);
    }
  };
  auto stageV = [&](int buf, int kv) {
#pragma unroll
    for (int i = 0; i < 8; ++i) {
      const int d = wave * 64 + i * 8 + (lane >> 3);
      const int gc = (lane & 7) ^ (d & 7);
      gload_lds16(Vtg + vtbase + (size_t)d * 4096 + kv + gc * 8,
                  &sVt[buf][(wave * 64 + i * 8) * 64]);
    }
  };

  stageK(0, 0);
  stageV(0, 0);

  for (int t = 0; t < 32; ++t) {
    const int cur = t & 1;
    __syncthreads();  // drains DMA for buf[cur]; guards buf[cur^1] reuse
    if (t < 31) {
      stageK(cur ^ 1, (t + 1) * 64);
      stageV(cur ^ 1, (t + 1) * 64);
    }

    // QK^T swapped: accS[kb] holds S[k][q]; q = l31 (lane-local row!),
    // k = kb*32 + (r&3) + 8*(r>>2) + 4*hi.
    f32x16 accS[2];
#pragma unroll
    for (int kb = 0; kb < 2; ++kb)
#pragma unroll
      for (int j = 0; j < 16; ++j) accS[kb][j] = 0.f;
    const __bf16* kb_ = sK[cur];
#pragma unroll
    for (int kb = 0; kb < 2; ++kb) {
      const int kr = kb * 32 + l31;
#pragma unroll
      for (int dc = 0; dc < 8; ++dc) {
        bf8_t a = *(const bf8_t*)&kb_[kr * 128 + ((2 * dc + hi) ^ (kr & 7)) * 8];
        accS[kb] = MFMA32(a, qf[dc], accS[kb]);
      }
    }

    // row max: in-register tree + one cross-half exchange
    float pm = accS[0][0];
#pragma unroll
    for (int j = 1; j < 16; ++j) pm = fmaxf(pm, accS[0][j]);
#pragma unroll
    for (int j = 0; j < 16; ++j) pm = fmaxf(pm, accS[1][j]);
    pm = fmaxf(pm, __shfl_xor(pm, 32));

    // defer-max (T13): rescale only when some row max grows by > 8 (log2)
    if (__ballot(pm > m_ + 8.0f)) {
      const float mn = fmaxf(m_, pm);
      const float sc = exp2f(m_ - mn);
      m_ = mn;
      l_ *= sc;
      if (hi == 0) sW[wave][l31] = sc;
#pragma unroll
      for (int r = 0; r < 16; ++r) {
        const float scr = sW[wave][(r & 3) + 8 * (r >> 2) + 4 * hi];
#pragma unroll
        for (int db = 0; db < 4; ++db) accO[db][r] *= scr;
      }
    }

    // p = 2^(s - m), row sum
    float rs = 0.f;
#pragma unroll
    for (int kb = 0; kb < 2; ++kb)
#pragma unroll
      for (int j = 0; j < 16; ++j) {
        const float p = exp2f(accS[kb][j] - m_);
        accS[kb][j] = p;
        rs += p;
      }
    rs += __shfl_xor(rs, 32);
    l_ += rs;

    // pack P quads to bf16 u32-pairs: pk[kb][t] covers k = kb*32+t*8+4*hi+u
    unsigned pk[2][4][2];
#pragma unroll
    for (int kb = 0; kb < 2; ++kb)
#pragma unroll
      for (int tq = 0; tq < 4; ++tq) {
        pk[kb][tq][0] = pk2(accS[kb][4 * tq + 0], accS[kb][4 * tq + 1]);
        pk[kb][tq][1] = pk2(accS[kb][4 * tq + 2], accS[kb][4 * tq + 3]);
      }

    // PV: per k-chunk kc build A-frag via one lane-pair quad exchange
    const __bf16* vt_ = sVt[cur];
#pragma unroll
    for (int kc = 0; kc < 4; ++kc) {
      const int kb = kc >> 1, par = kc & 1;
      const unsigned own0 = hi ? pk[kb][2 * par + 1][0] : pk[kb][2 * par][0];
      const unsigned own1 = hi ? pk[kb][2 * par + 1][1] : pk[kb][2 * par][1];
      const unsigned snd0 = hi ? pk[kb][2 * par][0] : pk[kb][2 * par + 1][0];
      const unsigned snd1 = hi ? pk[kb][2 * par][1] : pk[kb][2 * par + 1][1];
      const unsigned rc0 = (unsigned)__shfl_xor((int)snd0, 32);
      const unsigned rc1 = (unsigned)__shfl_xor((int)snd1, 32);
      u32x4 fr;
      fr[0] = hi ? rc0 : own0;
      fr[1] = hi ? rc1 : own1;
      fr[2] = hi ? own0 : rc0;
      fr[3] = hi ? own1 : rc1;
      const bf8_t pa = __builtin_bit_cast(bf8_t, fr);
#pragma unroll
      for (int db = 0; db < 4; ++db) {
        const int dr = db * 32 + l31;
        bf8_t vb = *(const bf8_t*)&vt_[dr * 64 + ((2 * kc + hi) ^ (dr & 7)) * 8];
        accO[db] = MFMA32(pa, vb, accO[db]);
      }
    }
  }

  // epilogue: broadcast l per q-row, normalize, store
  if (hi == 0) sW[wave][l31] = l_;
#pragma unroll
  for (int r = 0; r < 16; ++r) {
    const int qr = (r & 3) + 8 * (r >> 2) + 4 * hi;
    const float linv = 1.0f / sW[wave][qr];
    __bf16* op = Og + base + (size_t)(q0 + qr) * D + l31;
#pragma unroll
    for (int db = 0; db < 4; ++db)
      op[db * 32] = (__bf16)(accO[db][r] * linv);
  }
}

// ---------------------------------------------------------------------------
// Kernel 4: output projection + bias + LoRA-up. bf16 GEMM, fp32 epilogue/out.
// ---------------------------------------------------------------------------
__global__ __launch_bounds__(256) void gemm_out_k(
    const __bf16* __restrict__ A, const __bf16* __restrict__ Wo,
    const float* __restrict__ bo, const float* __restrict__ lup,
    const float* __restrict__ tmp, float* __restrict__ out) {
  __shared__ __bf16 sA[128 * 64];
  __shared__ __bf16 sB[128 * 64];
  const int bcol = blockIdx.x, brow = blockIdx.y;
  const int K = 1024, N = 1024;
  f32x4 acc[4][4];
  gemm_tile(A + (size_t)brow * 128 * K, Wo + (size_t)bcol * 128 * K, K, sA, sB, acc);

  const int lane = threadIdx.x & 63, wave = threadIdx.x >> 6;
  const int wr = (wave >> 1) * 64, wc = (wave & 1) * 64;
  for (int n = 0; n < 4; ++n) {
    const int col = bcol * 128 + wc + n * 16 + (lane & 15);
    const float bias = bo[col];
    const float u0 = lup[col * 4 + 0], u1 = lup[col * 4 + 1];
    const float u2 = lup[col * 4 + 2], u3 = lup[col * 4 + 3];
    for (int m = 0; m < 4; ++m)
      for (int j = 0; j < 4; ++j) {
        const int row = brow * 128 + wr + m * 16 + (lane >> 4) * 4 + j;
        const float* t = tmp + row * 4;
        float v = acc[m][n][j] + bias + t[0] * u0 + t[1] * u1 + t[2] * u2 + t[3] * u3;
        out[(size_t)row * N + col] = v;
      }
  }
}

// ---------------------------------------------------------------------------
extern "C" void kernel_launch(void* const* d_in, const int* in_sizes, int n_in,
                              void* d_out, int out_size, void* d_ws, size_t ws_size,
                              hipStream_t stream) {
  (void)in_sizes; (void)n_in; (void)out_size; (void)ws_size;
  const float* hs  = (const float*)d_in[0];
  const float* cs  = (const float*)d_in[1];
  const float* Wq  = (const float*)d_in[2];
  const float* Wk  = (const float*)d_in[3];
  const float* Wv  = (const float*)d_in[4];
  const float* Wo  = (const float*)d_in[5];
  const float* bo  = (const float*)d_in[6];
  const float* ldw = (const float*)d_in[7];
  const float* lup = (const float*)d_in[8];
  float* out = (float*)d_out;

  const size_t MD = (size_t)4096 * 1024;   // B*S*D
  const size_t WD = (size_t)1024 * 1024;   // D*D
  __bf16* hsb = (__bf16*)d_ws;
  __bf16* Wqb = hsb + MD;
  __bf16* Wkb = Wqb + WD;
  __bf16* Wvb = Wkb + WD;
  __bf16* Wob = Wvb + WD;
  __bf16* Qb  = Wob + WD;
  __bf16* Kb  = Qb + MD;
  __bf16* Vtb = Kb + MD;   // V^T: [h*128+d][b*2048+s] = [1024][4096]
  __bf16* Ab  = Vtb + MD;
  float*  tmp = (float*)(Ab + MD);

  cvt5_k<<<dim3(2048, 5), 256, 0, stream>>>(hs, Wq, Wk, Wv, Wo,
                                            hsb, Wqb, Wkb, Wvb, Wob);
  gemm_qkv_k<<<dim3(8, 32, 3), 256, 0, stream>>>(hsb, Wqb, Wkb, Wvb, Qb, Kb, Vtb);
  lora_down_k<<<dim3(1024), 256, 0, stream>>>(cs, ldw, tmp);
  flash_attn_k<<<dim3(32, 16), 128, 0, stream>>>(Qb, Kb, Vtb, Ab);
  gemm_out_k<<<dim3(8, 32), 256, 0, stream>>>(Ab, Wob, bo, lup, tmp, out);
}

// Round 6
// 169.235 us; speedup vs baseline: 1.8374x; 1.0400x over previous
//
#include <hip/hip_runtime.h>
#include <hip/hip_bf16.h>

// B=2, S=2048, D=1024, H=8, HD=128, RANK=4.
// Device I/O buffers are FP32 (per reference dtypes).
// Internal pipeline: convert to bf16 in d_ws, bf16 MFMA with fp32 accum.
// V is produced TRANSPOSED by the QKV GEMM (operand swap). Flash attention
// uses swapped QK^T (mfma(K,Q)) 32x32x16 with fully in-register softmax;
// KV range is SPLIT across blockIdx.z (2 halves) with KVBLK=32 tiles so
// LDS=32KB -> 4 blocks/CU -> 2 waves/SIMD (TLP for MFMA/VALU overlap).
// Partial (unnormalized O, m, l) per half merged by a small epilogue kernel.

typedef __bf16 bf8_t __attribute__((ext_vector_type(8)));
typedef float f32x4 __attribute__((ext_vector_type(4)));
typedef float f32x16 __attribute__((ext_vector_type(16)));
typedef unsigned u32x4 __attribute__((ext_vector_type(4)));

#define MFMA16(a, b, c) __builtin_amdgcn_mfma_f32_16x16x32_bf16((a), (b), (c), 0, 0, 0)
#define MFMA32(a, b, c) __builtin_amdgcn_mfma_f32_32x32x16_bf16((a), (b), (c), 0, 0, 0)

__device__ __forceinline__ void gload_lds16(const void* g, void* l) {
  __builtin_amdgcn_global_load_lds(
      (const __attribute__((address_space(1))) void*)g,
      (__attribute__((address_space(3))) void*)l, 16, 0, 0);
}

__device__ __forceinline__ unsigned pk2(float a, float b) {
  unsigned short ua = __builtin_bit_cast(unsigned short, (__bf16)a);
  unsigned short ub = __builtin_bit_cast(unsigned short, (__bf16)b);
  return (unsigned)ua | ((unsigned)ub << 16);
}

// ---------------------------------------------------------------------------
// Kernel 0: fp32 -> bf16 conversion (hidden_states + Wq,Wk,Wv,Wo).
// ---------------------------------------------------------------------------
__global__ __launch_bounds__(256) void cvt5_k(
    const float* __restrict__ s0, const float* __restrict__ s1,
    const float* __restrict__ s2, const float* __restrict__ s3,
    const float* __restrict__ s4, __bf16* __restrict__ d0,
    __bf16* __restrict__ d1, __bf16* __restrict__ d2, __bf16* __restrict__ d3,
    __bf16* __restrict__ d4) {
  const int which = blockIdx.y;
  const float* s = (which == 0) ? s0 : (which == 1) ? s1 : (which == 2) ? s2
                   : (which == 3) ? s3 : s4;
  __bf16* d = (which == 0) ? d0 : (which == 1) ? d1 : (which == 2) ? d2
              : (which == 3) ? d3 : d4;
  const int n = (which == 0) ? (4096 * 1024) : (1024 * 1024);
  const int i = (blockIdx.x * 256 + threadIdx.x) * 8;
  if (i >= n) return;
  float4 a = *(const float4*)(s + i);
  float4 b = *(const float4*)(s + i + 4);
  bf8_t r;
  r[0] = (__bf16)a.x; r[1] = (__bf16)a.y; r[2] = (__bf16)a.z; r[3] = (__bf16)a.w;
  r[4] = (__bf16)b.x; r[5] = (__bf16)b.y; r[6] = (__bf16)b.z; r[7] = (__bf16)b.w;
  *(bf8_t*)(d + i) = r;
}

// ---------------------------------------------------------------------------
// GEMM tile body: C[128,128] = A[128,K] * W[128(cols),K]^T (NT). 4 waves,
// each a 64x64 sub-tile = 4x4 fragments of 16x16, BK=64. LDS linear [128][64].
// ---------------------------------------------------------------------------
__device__ __forceinline__ void gemm_tile(const __bf16* __restrict__ Abase,
                                          const __bf16* __restrict__ Wbase,
                                          int K, __bf16* sA, __bf16* sB,
                                          f32x4 acc[4][4]) {
  const int tid = threadIdx.x;
  const int wave = tid >> 6, lane = tid & 63;
  const int wr = (wave >> 1) * 64, wc = (wave & 1) * 64;
  const int lrow = lane >> 3, lchunk = lane & 7;

  for (int m = 0; m < 4; ++m)
    for (int n = 0; n < 4; ++n)
      acc[m][n] = f32x4{0.f, 0.f, 0.f, 0.f};

  for (int k0 = 0; k0 < K; k0 += 64) {
    for (int i = 0; i < 4; ++i) {
      const int rbase = i * 32 + wave * 8;
      gload_lds16(Abase + (size_t)(rbase + lrow) * K + k0 + lchunk * 8,
                  sA + rbase * 64);
      gload_lds16(Wbase + (size_t)(rbase + lrow) * K + k0 + lchunk * 8,
                  sB + rbase * 64);
    }
    __syncthreads();

    for (int kk = 0; kk < 2; ++kk) {
      bf8_t af[4], bfr[4];
      const int koff = kk * 32 + (lane >> 4) * 8;
      for (int m = 0; m < 4; ++m)
        af[m] = *(const bf8_t*)&sA[(wr + m * 16 + (lane & 15)) * 64 + koff];
      for (int n = 0; n < 4; ++n)
        bfr[n] = *(const bf8_t*)&sB[(wc + n * 16 + (lane & 15)) * 64 + koff];
      for (int m = 0; m < 4; ++m)
        for (int n = 0; n < 4; ++n)
          acc[m][n] = MFMA16(af[m], bfr[n], acc[m][n]);
    }
    __syncthreads();
  }
}

// ---------------------------------------------------------------------------
// Kernel 1: QKV projections. z==0/1: C = X.W^T; z==2: operands swapped so the
// output IS V^T: Vt[h*128+d][b*2048+s] (row-major [1024][4096]).
// ---------------------------------------------------------------------------
__global__ __launch_bounds__(256) void gemm_qkv_k(
    const __bf16* __restrict__ X, const __bf16* __restrict__ Wq,
    const __bf16* __restrict__ Wk, const __bf16* __restrict__ Wv,
    __bf16* __restrict__ Qb, __bf16* __restrict__ Kb, __bf16* __restrict__ Vtb) {
  __shared__ __bf16 sA[128 * 64];
  __shared__ __bf16 sB[128 * 64];
  const int z = blockIdx.z;
  const int K = 1024;
  int rowT, colT, Nout;
  const __bf16 *Abase, *Wbase;
  __bf16* C;
  if (z == 2) {
    rowT = blockIdx.x; colT = blockIdx.y; Nout = 4096;
    Abase = Wv + (size_t)rowT * 128 * K;
    Wbase = X + (size_t)colT * 128 * K;
    C = Vtb;
  } else {
    rowT = blockIdx.y; colT = blockIdx.x; Nout = 1024;
    Abase = X + (size_t)rowT * 128 * K;
    Wbase = ((z == 0) ? Wq : Wk) + (size_t)colT * 128 * K;
    C = (z == 0) ? Qb : Kb;
  }
  f32x4 acc[4][4];
  gemm_tile(Abase, Wbase, K, sA, sB, acc);

  const int lane = threadIdx.x & 63, wave = threadIdx.x >> 6;
  const int wr = (wave >> 1) * 64, wc = (wave & 1) * 64;
  const int row0 = rowT * 128 + wr + (lane >> 4) * 4;
  const int col0 = colT * 128 + wc + (lane & 15);
  for (int m = 0; m < 4; ++m)
    for (int n = 0; n < 4; ++n)
      for (int j = 0; j < 4; ++j)
        C[(size_t)(row0 + m * 16 + j) * Nout + col0 + n * 16] = (__bf16)acc[m][n][j];
}

// ---------------------------------------------------------------------------
// Kernel 2: LoRA down: tmp[s][r] = sum_d control[s][d]*down[r][d]. FP32 in.
// ---------------------------------------------------------------------------
__global__ __launch_bounds__(256) void lora_down_k(
    const float* __restrict__ ctrl, const float* __restrict__ down,
    float* __restrict__ tmp) {
  const int tid = threadIdx.x, wave = tid >> 6, lane = tid & 63;
  const int s = blockIdx.x * 4 + wave;
  const float* cp = ctrl + (size_t)s * 1024 + lane * 16;
  float4 c[4];
  for (int i = 0; i < 4; ++i) c[i] = *(const float4*)(cp + i * 4);
  for (int r = 0; r < 4; ++r) {
    const float* dp = down + r * 1024 + lane * 16;
    float acc = 0.f;
    for (int i = 0; i < 4; ++i) {
      float4 dv = *(const float4*)(dp + i * 4);
      acc += c[i].x * dv.x + c[i].y * dv.y + c[i].z * dv.z + c[i].w * dv.w;
    }
    for (int off = 32; off > 0; off >>= 1) acc += __shfl_xor(acc, off);
    if (lane == 0) tmp[s * 4 + r] = acc;
  }
}

// ---------------------------------------------------------------------------
// Kernel 3: flash attention partial pass, swapped-QK^T 32x32 structure.
// grid (32 q-tiles, 16 bh, 2 kv-halves) = 1024 blocks, 128 thr = 2 waves;
// wave owns 32 q-rows; KVBLK=32; LDS 32.3 KB -> 4 blocks/CU -> 2 waves/SIMD.
//   sK [2][32][128]  dbuf, chunk-XOR swizzle (pos(r,c) holds K[r][c^(r&7)])
//   sVt [2][128][32] dbuf, chunk-XOR on 4-chunk rows (c holds chunk c^(d&3))
// Writes UNNORMALIZED partial O (bf16) + per-q (m, l) f32; merged later.
// ---------------------------------------------------------------------------
__global__ __launch_bounds__(128) void flash_attn_k(
    const __bf16* __restrict__ Qg, const __bf16* __restrict__ Kg,
    const __bf16* __restrict__ Vtg, __bf16* __restrict__ Op,
    float* __restrict__ ml) {
  const int S = 2048, D = 1024;
  __shared__ __bf16 sK[2][32 * 128];
  __shared__ __bf16 sVt[2][128 * 32];
  __shared__ float sW[2][32];
  const int qt = blockIdx.x, bh = blockIdx.y, z = blockIdx.z;
  const int b = bh >> 3, h = bh & 7;
  const int tid = threadIdx.x, wave = tid >> 6, lane = tid & 63;
  const int l31 = lane & 31, hi = lane >> 5;
  const size_t base = (size_t)b * S * D + (size_t)h * 128;
  const size_t vtbase = (size_t)h * 128 * 4096 + (size_t)b * 2048;
  const int q0 = qt * 64 + wave * 32;
  const int kvbase = z * 1024;

  // Q as B-fragments, pre-scaled by (1/sqrt(128))*log2(e) (exp2 domain).
  bf8_t qf[8];
  {
    const float c = 0.08838834764831845f * 1.4426950408889634f;
    const __bf16* qp = Qg + base + (size_t)(q0 + l31) * D + hi * 8;
#pragma unroll
    for (int dc = 0; dc < 8; ++dc) {
      bf8_t v = *(const bf8_t*)(qp + dc * 16);
#pragma unroll
      for (int j = 0; j < 8; ++j) v[j] = (__bf16)((float)v[j] * c);
      qf[dc] = v;
    }
  }

  f32x16 accO[4];
#pragma unroll
  for (int db = 0; db < 4; ++db)
#pragma unroll
    for (int j = 0; j < 16; ++j) accO[db][j] = 0.f;
  float m_ = -1e30f, l_ = 0.f;

  auto stageK = [&](int buf, int kv) {
#pragma unroll
    for (int i = 0; i < 4; ++i) {
      const int r = wave * 16 + i * 4 + (lane >> 4);
      const int gc = (lane & 15) ^ (r & 7);
      gload_lds16(Kg + base + (size_t)(kv + r) * D + gc * 8,
                  &sK[buf][(wave * 16 + i * 4) * 128]);
    }
  };
  auto stageV = [&](int buf, int kv) {
#pragma unroll
    for (int i = 0; i < 4; ++i) {
      const int d = wave * 64 + i * 16 + (lane >> 2);
      const int gc = (lane & 3) ^ (d & 3);
      gload_lds16(Vtg + vtbase + (size_t)d * 4096 + kv + gc * 8,
                  &sVt[buf][(wave * 64 + i * 16) * 32]);
    }
  };

  stageK(0, kvbase);
  stageV(0, kvbase);

  for (int t = 0; t < 32; ++t) {
    const int cur = t & 1;
    __syncthreads();  // drains DMA for buf[cur]; guards buf[cur^1] reuse
    if (t < 31) {
      stageK(cur ^ 1, kvbase + (t + 1) * 32);
      stageV(cur ^ 1, kvbase + (t + 1) * 32);
    }

    // QK^T swapped: accS holds S[k][q]; q = l31 (lane-local row),
    // k = (r&3) + 8*(r>>2) + 4*hi.
    f32x16 accS;
#pragma unroll
    for (int j = 0; j < 16; ++j) accS[j] = 0.f;
    const __bf16* kb_ = sK[cur];
    const int kr = l31;
#pragma unroll
    for (int dc = 0; dc < 8; ++dc) {
      bf8_t a = *(const bf8_t*)&kb_[kr * 128 + ((2 * dc + hi) ^ (kr & 7)) * 8];
      accS = MFMA32(a, qf[dc], accS);
    }

    // row max: in-register tree + one cross-half exchange
    float pm = accS[0];
#pragma unroll
    for (int j = 1; j < 16; ++j) pm = fmaxf(pm, accS[j]);
    pm = fmaxf(pm, __shfl_xor(pm, 32));

    // defer-max (T13): rescale only when some row max grows by > 8 (log2)
    if (__ballot(pm > m_ + 8.0f)) {
      const float mn = fmaxf(m_, pm);
      const float sc = exp2f(m_ - mn);
      m_ = mn;
      l_ *= sc;
      if (hi == 0) sW[wave][l31] = sc;
#pragma unroll
      for (int r = 0; r < 16; ++r) {
        const float scr = sW[wave][(r & 3) + 8 * (r >> 2) + 4 * hi];
#pragma unroll
        for (int db = 0; db < 4; ++db) accO[db][r] *= scr;
      }
    }

    // p = 2^(s - m), row sum
    float rs = 0.f;
#pragma unroll
    for (int j = 0; j < 16; ++j) {
      const float p = exp2f(accS[j] - m_);
      accS[j] = p;
      rs += p;
    }
    rs += __shfl_xor(rs, 32);
    l_ += rs;

    // pack P quads: pk[tq] covers k = 8*tq + 4*hi + {0..3}
    unsigned pk[4][2];
#pragma unroll
    for (int tq = 0; tq < 4; ++tq) {
      pk[tq][0] = pk2(accS[4 * tq + 0], accS[4 * tq + 1]);
      pk[tq][1] = pk2(accS[4 * tq + 2], accS[4 * tq + 3]);
    }

    // PV: 2 K=16 slices; A-frag via one lane-pair quad exchange per slice
    const __bf16* vt_ = sVt[cur];
#pragma unroll
    for (int kc = 0; kc < 2; ++kc) {
      const unsigned own0 = hi ? pk[2 * kc + 1][0] : pk[2 * kc][0];
      const unsigned own1 = hi ? pk[2 * kc + 1][1] : pk[2 * kc][1];
      const unsigned snd0 = hi ? pk[2 * kc][0] : pk[2 * kc + 1][0];
      const unsigned snd1 = hi ? pk[2 * kc][1] : pk[2 * kc + 1][1];
      const unsigned rc0 = (unsigned)__shfl_xor((int)snd0, 32);
      const unsigned rc1 = (unsigned)__shfl_xor((int)snd1, 32);
      u32x4 fr;
      fr[0] = hi ? rc0 : own0;
      fr[1] = hi ? rc1 : own1;
      fr[2] = hi ? own0 : rc0;
      fr[3] = hi ? own1 : rc1;
      const bf8_t pa = __builtin_bit_cast(bf8_t, fr);
#pragma unroll
      for (int db = 0; db < 4; ++db) {
        const int dr = db * 32 + l31;
        bf8_t vb = *(const bf8_t*)&vt_[dr * 32 + ((kc * 2 + hi) ^ (dr & 3)) * 8];
        accO[db] = MFMA32(pa, vb, accO[db]);
      }
    }
  }

  // partial epilogue: unnormalized O (bf16) + (m,l) per q-row
  const size_t pbase = ((size_t)(z * 16 + bh) * 2048 + q0);
#pragma unroll
  for (int r = 0; r < 16; ++r) {
    const int qr = (r & 3) + 8 * (r >> 2) + 4 * hi;
    __bf16* op = Op + (pbase + qr) * 128 + l31;
#pragma unroll
    for (int db = 0; db < 4; ++db)
      op[db * 32] = (__bf16)(accO[db][r]);
  }
  if (hi == 0) {
    ml[(pbase + l31) * 2 + 0] = m_;
    ml[(pbase + l31) * 2 + 1] = l_;
  }
}

// ---------------------------------------------------------------------------
// Kernel 3b: merge the two KV-half partials.
// O = (O0*w0 + O1*w1) / (l0*w0 + l1*w1), wi = 2^(mi - max(m0,m1)).
// grid 2048 blocks x 256 thr: block = (bh, 16-q chunk); thread = (q, 8-d grp).
// ---------------------------------------------------------------------------
__global__ __launch_bounds__(256) void attn_merge_k(
    const __bf16* __restrict__ Op, const float* __restrict__ ml,
    __bf16* __restrict__ Og) {
  const int bh = blockIdx.x >> 7, qc = blockIdx.x & 127;
  const int t = threadIdx.x;
  const int qr = qc * 16 + (t >> 4);
  const int d0 = (t & 15) * 8;
  const int b = bh >> 3, h = bh & 7;

  const size_t i0 = ((size_t)bh * 2048 + qr);
  const size_t i1 = ((size_t)(16 + bh) * 2048 + qr);
  const float m0 = ml[i0 * 2], l0 = ml[i0 * 2 + 1];
  const float m1 = ml[i1 * 2], l1 = ml[i1 * 2 + 1];
  const float m = fmaxf(m0, m1);
  const float w0 = exp2f(m0 - m), w1 = exp2f(m1 - m);
  const float inv = 1.0f / (l0 * w0 + l1 * w1);

  bf8_t o0 = *(const bf8_t*)(Op + i0 * 128 + d0);
  bf8_t o1 = *(const bf8_t*)(Op + i1 * 128 + d0);
  bf8_t r;
#pragma unroll
  for (int j = 0; j < 8; ++j)
    r[j] = (__bf16)(((float)o0[j] * w0 + (float)o1[j] * w1) * inv);
  *(bf8_t*)(Og + ((size_t)(b * 2048 + qr) * 1024) + h * 128 + d0) = r;
}

// ---------------------------------------------------------------------------
// Kernel 4: output projection + bias + LoRA-up. bf16 GEMM, fp32 epilogue/out.
// ---------------------------------------------------------------------------
__global__ __launch_bounds__(256) void gemm_out_k(
    const __bf16* __restrict__ A, const __bf16* __restrict__ Wo,
    const float* __restrict__ bo, const float* __restrict__ lup,
    const float* __restrict__ tmp, float* __restrict__ out) {
  __shared__ __bf16 sA[128 * 64];
  __shared__ __bf16 sB[128 * 64];
  const int bcol = blockIdx.x, brow = blockIdx.y;
  const int K = 1024, N = 1024;
  f32x4 acc[4][4];
  gemm_tile(A + (size_t)brow * 128 * K, Wo + (size_t)bcol * 128 * K, K, sA, sB, acc);

  const int lane = threadIdx.x & 63, wave = threadIdx.x >> 6;
  const int wr = (wave >> 1) * 64, wc = (wave & 1) * 64;
  for (int n = 0; n < 4; ++n) {
    const int col = bcol * 128 + wc + n * 16 + (lane & 15);
    const float bias = bo[col];
    const float u0 = lup[col * 4 + 0], u1 = lup[col * 4 + 1];
    const float u2 = lup[col * 4 + 2], u3 = lup[col * 4 + 3];
    for (int m = 0; m < 4; ++m)
      for (int j = 0; j < 4; ++j) {
        const int row = brow * 128 + wr + m * 16 + (lane >> 4) * 4 + j;
        const float* t = tmp + row * 4;
        float v = acc[m][n][j] + bias + t[0] * u0 + t[1] * u1 + t[2] * u2 + t[3] * u3;
        out[(size_t)row * N + col] = v;
      }
  }
}

// ---------------------------------------------------------------------------
extern "C" void kernel_launch(void* const* d_in, const int* in_sizes, int n_in,
                              void* d_out, int out_size, void* d_ws, size_t ws_size,
                              hipStream_t stream) {
  (void)in_sizes; (void)n_in; (void)out_size; (void)ws_size;
  const float* hs  = (const float*)d_in[0];
  const float* cs  = (const float*)d_in[1];
  const float* Wq  = (const float*)d_in[2];
  const float* Wk  = (const float*)d_in[3];
  const float* Wv  = (const float*)d_in[4];
  const float* Wo  = (const float*)d_in[5];
  const float* bo  = (const float*)d_in[6];
  const float* ldw = (const float*)d_in[7];
  const float* lup = (const float*)d_in[8];
  float* out = (float*)d_out;

  const size_t MD = (size_t)4096 * 1024;   // B*S*D
  const size_t WD = (size_t)1024 * 1024;   // D*D
  __bf16* hsb = (__bf16*)d_ws;
  __bf16* Wqb = hsb + MD;
  __bf16* Wkb = Wqb + WD;
  __bf16* Wvb = Wkb + WD;
  __bf16* Wob = Wvb + WD;
  __bf16* Qb  = Wob + WD;
  __bf16* Kb  = Qb + MD;
  __bf16* Vtb = Kb + MD;   // V^T: [h*128+d][b*2048+s] = [1024][4096]
  __bf16* Ab  = Vtb + MD;
  float*  tmp = (float*)(Ab + MD);              // [4096][4]
  __bf16* Opart = (__bf16*)(tmp + 4096 * 4);    // [2][16][2048][128] bf16
  float*  mlp   = (float*)(Opart + (size_t)2 * 16 * 2048 * 128);  // [2][16][2048][2]

  cvt5_k<<<dim3(2048, 5), 256, 0, stream>>>(hs, Wq, Wk, Wv, Wo,
                                            hsb, Wqb, Wkb, Wvb, Wob);
  gemm_qkv_k<<<dim3(8, 32, 3), 256, 0, stream>>>(hsb, Wqb, Wkb, Wvb, Qb, Kb, Vtb);
  lora_down_k<<<dim3(1024), 256, 0, stream>>>(cs, ldw, tmp);
  flash_attn_k<<<dim3(32, 16, 2), 128, 0, stream>>>(Qb, Kb, Vtb, Opart, mlp);
  attn_merge_k<<<dim3(2048), 256, 0, stream>>>(Opart, mlp, Ab);
  gemm_out_k<<<dim3(8, 32), 256, 0, stream>>>(Ab, Wob, bo, lup, tmp, out);
}

// Round 7
// 164.675 us; speedup vs baseline: 1.8883x; 1.0277x over previous
//
#include <hip/hip_runtime.h>
#include <hip/hip_bf16.h>

// B=2, S=2048, D=1024, H=8, HD=128, RANK=4.
// Device I/O buffers are FP32 (per reference dtypes).
// Internal pipeline: convert to bf16 in d_ws, bf16 MFMA with fp32 accum.
// V is produced TRANSPOSED by the QKV GEMM (operand swap). Flash attention:
// swapped QK^T (mfma(K,Q)) 32x32x16, in-register softmax, KV split across
// blockIdx.z, KVBLK=32, V-slot swizzle f(d)=(d>>1)&3 (decorrelated from the
// row-parity bank bit -> bank-minimum b128 reads), setprio around MFMA.

typedef __bf16 bf8_t __attribute__((ext_vector_type(8)));
typedef float f32x4 __attribute__((ext_vector_type(4)));
typedef float f32x16 __attribute__((ext_vector_type(16)));
typedef unsigned u32x4 __attribute__((ext_vector_type(4)));

#define MFMA16(a, b, c) __builtin_amdgcn_mfma_f32_16x16x32_bf16((a), (b), (c), 0, 0, 0)
#define MFMA32(a, b, c) __builtin_amdgcn_mfma_f32_32x32x16_bf16((a), (b), (c), 0, 0, 0)

__device__ __forceinline__ void gload_lds16(const void* g, void* l) {
  __builtin_amdgcn_global_load_lds(
      (const __attribute__((address_space(1))) void*)g,
      (__attribute__((address_space(3))) void*)l, 16, 0, 0);
}

__device__ __forceinline__ unsigned pk2(float a, float b) {
  unsigned short ua = __builtin_bit_cast(unsigned short, (__bf16)a);
  unsigned short ub = __builtin_bit_cast(unsigned short, (__bf16)b);
  return (unsigned)ua | ((unsigned)ub << 16);
}

// ---------------------------------------------------------------------------
// Kernel 0: fp32 -> bf16 conversion (hidden_states + Wq,Wk,Wv,Wo).
// ---------------------------------------------------------------------------
__global__ __launch_bounds__(256) void cvt5_k(
    const float* __restrict__ s0, const float* __restrict__ s1,
    const float* __restrict__ s2, const float* __restrict__ s3,
    const float* __restrict__ s4, __bf16* __restrict__ d0,
    __bf16* __restrict__ d1, __bf16* __restrict__ d2, __bf16* __restrict__ d3,
    __bf16* __restrict__ d4) {
  const int which = blockIdx.y;
  const float* s = (which == 0) ? s0 : (which == 1) ? s1 : (which == 2) ? s2
                   : (which == 3) ? s3 : s4;
  __bf16* d = (which == 0) ? d0 : (which == 1) ? d1 : (which == 2) ? d2
              : (which == 3) ? d3 : d4;
  const int n = (which == 0) ? (4096 * 1024) : (1024 * 1024);
  const int i = (blockIdx.x * 256 + threadIdx.x) * 8;
  if (i >= n) return;
  float4 a = *(const float4*)(s + i);
  float4 b = *(const float4*)(s + i + 4);
  bf8_t r;
  r[0] = (__bf16)a.x; r[1] = (__bf16)a.y; r[2] = (__bf16)a.z; r[3] = (__bf16)a.w;
  r[4] = (__bf16)b.x; r[5] = (__bf16)b.y; r[6] = (__bf16)b.z; r[7] = (__bf16)b.w;
  *(bf8_t*)(d + i) = r;
}

// ---------------------------------------------------------------------------
// GEMM tile body, templated on per-wave M-fragments MR (tile = MR*32 x 128).
// C[MR*32,128] = A[MR*32,K] * W[128(cols),K]^T (NT). 4 waves (2x2); each
// wave owns (MR*16)x64 = MRx4 fragments of 16x16, BK=64.
// ---------------------------------------------------------------------------
template <int MR>
__device__ __forceinline__ void gemm_tile(const __bf16* __restrict__ Abase,
                                          const __bf16* __restrict__ Wbase,
                                          int K, __bf16* sA, __bf16* sB,
                                          f32x4 acc[MR][4]) {
  const int tid = threadIdx.x;
  const int wave = tid >> 6, lane = tid & 63;
  const int wr = (wave >> 1) * (MR * 16), wc = (wave & 1) * 64;
  const int lrow = lane >> 3, lchunk = lane & 7;

  for (int m = 0; m < MR; ++m)
    for (int n = 0; n < 4; ++n)
      acc[m][n] = f32x4{0.f, 0.f, 0.f, 0.f};

  for (int k0 = 0; k0 < K; k0 += 64) {
    for (int i = 0; i < MR; ++i) {
      const int rbase = i * 32 + wave * 8;
      gload_lds16(Abase + (size_t)(rbase + lrow) * K + k0 + lchunk * 8,
                  sA + rbase * 64);
    }
    for (int i = 0; i < 4; ++i) {
      const int rbase = i * 32 + wave * 8;
      gload_lds16(Wbase + (size_t)(rbase + lrow) * K + k0 + lchunk * 8,
                  sB + rbase * 64);
    }
    __syncthreads();

    for (int kk = 0; kk < 2; ++kk) {
      bf8_t af[MR], bfr[4];
      const int koff = kk * 32 + (lane >> 4) * 8;
      for (int m = 0; m < MR; ++m)
        af[m] = *(const bf8_t*)&sA[(wr + m * 16 + (lane & 15)) * 64 + koff];
      for (int n = 0; n < 4; ++n)
        bfr[n] = *(const bf8_t*)&sB[(wc + n * 16 + (lane & 15)) * 64 + koff];
      for (int m = 0; m < MR; ++m)
        for (int n = 0; n < 4; ++n)
          acc[m][n] = MFMA16(af[m], bfr[n], acc[m][n]);
    }
    __syncthreads();
  }
}

// ---------------------------------------------------------------------------
// Kernel 1: QKV projections. z==0/1: C = X.W^T; z==2: operands swapped so the
// output IS V^T: Vt[h*128+d][b*2048+s] (row-major [1024][4096]).
// ---------------------------------------------------------------------------
__global__ __launch_bounds__(256) void gemm_qkv_k(
    const __bf16* __restrict__ X, const __bf16* __restrict__ Wq,
    const __bf16* __restrict__ Wk, const __bf16* __restrict__ Wv,
    __bf16* __restrict__ Qb, __bf16* __restrict__ Kb, __bf16* __restrict__ Vtb) {
  __shared__ __bf16 sA[128 * 64];
  __shared__ __bf16 sB[128 * 64];
  const int z = blockIdx.z;
  const int K = 1024;
  int rowT, colT, Nout;
  const __bf16 *Abase, *Wbase;
  __bf16* C;
  if (z == 2) {
    rowT = blockIdx.x; colT = blockIdx.y; Nout = 4096;
    Abase = Wv + (size_t)rowT * 128 * K;
    Wbase = X + (size_t)colT * 128 * K;
    C = Vtb;
  } else {
    rowT = blockIdx.y; colT = blockIdx.x; Nout = 1024;
    Abase = X + (size_t)rowT * 128 * K;
    Wbase = ((z == 0) ? Wq : Wk) + (size_t)colT * 128 * K;
    C = (z == 0) ? Qb : Kb;
  }
  f32x4 acc[4][4];
  gemm_tile<4>(Abase, Wbase, K, sA, sB, acc);

  const int lane = threadIdx.x & 63, wave = threadIdx.x >> 6;
  const int wr = (wave >> 1) * 64, wc = (wave & 1) * 64;
  const int row0 = rowT * 128 + wr + (lane >> 4) * 4;
  const int col0 = colT * 128 + wc + (lane & 15);
  for (int m = 0; m < 4; ++m)
    for (int n = 0; n < 4; ++n)
      for (int j = 0; j < 4; ++j)
        C[(size_t)(row0 + m * 16 + j) * Nout + col0 + n * 16] = (__bf16)acc[m][n][j];
}

// ---------------------------------------------------------------------------
// Kernel 2: LoRA down: tmp[s][r] = sum_d control[s][d]*down[r][d]. FP32 in.
// ---------------------------------------------------------------------------
__global__ __launch_bounds__(256) void lora_down_k(
    const float* __restrict__ ctrl, const float* __restrict__ down,
    float* __restrict__ tmp) {
  const int tid = threadIdx.x, wave = tid >> 6, lane = tid & 63;
  const int s = blockIdx.x * 4 + wave;
  const float* cp = ctrl + (size_t)s * 1024 + lane * 16;
  float4 c[4];
  for (int i = 0; i < 4; ++i) c[i] = *(const float4*)(cp + i * 4);
  for (int r = 0; r < 4; ++r) {
    const float* dp = down + r * 1024 + lane * 16;
    float acc = 0.f;
    for (int i = 0; i < 4; ++i) {
      float4 dv = *(const float4*)(dp + i * 4);
      acc += c[i].x * dv.x + c[i].y * dv.y + c[i].z * dv.z + c[i].w * dv.w;
    }
    for (int off = 32; off > 0; off >>= 1) acc += __shfl_xor(acc, off);
    if (lane == 0) tmp[s * 4 + r] = acc;
  }
}

// ---------------------------------------------------------------------------
// Kernel 3: flash attention partial pass, swapped-QK^T 32x32 structure.
// grid (32 q-tiles, 16 bh, 2 kv-halves), 128 thr = 2 waves; wave owns 32
// q-rows; KVBLK=32; LDS 32.3 KB -> 4 blocks/CU -> 2 waves/SIMD.
//   sK [2][32][128]  dbuf; pos(r,c) holds K[r][c^(r&7)] (src pre-swizzle)
//   sVt [2][128][32] dbuf; pos(d,p) holds chunk p^((d>>1)&3) -- decorrelated
//                    from row parity so b128 reads hit the 32-bank minimum
// Writes UNNORMALIZED partial O (bf16) + per-q (m, l) f32; merged later.
// ---------------------------------------------------------------------------
__global__ __launch_bounds__(128) void flash_attn_k(
    const __bf16* __restrict__ Qg, const __bf16* __restrict__ Kg,
    const __bf16* __restrict__ Vtg, __bf16* __restrict__ Op,
    float* __restrict__ ml) {
  const int S = 2048, D = 1024;
  __shared__ __bf16 sK[2][32 * 128];
  __shared__ __bf16 sVt[2][128 * 32];
  __shared__ float sW[2][32];
  const int qt = blockIdx.x, bh = blockIdx.y, z = blockIdx.z;
  const int b = bh >> 3, h = bh & 7;
  const int tid = threadIdx.x, wave = tid >> 6, lane = tid & 63;
  const int l31 = lane & 31, hi = lane >> 5;
  const size_t base = (size_t)b * S * D + (size_t)h * 128;
  const size_t vtbase = (size_t)h * 128 * 4096 + (size_t)b * 2048;
  const int q0 = qt * 64 + wave * 32;
  const int kvbase = z * 1024;

  // Q as B-fragments, pre-scaled by (1/sqrt(128))*log2(e) (exp2 domain).
  bf8_t qf[8];
  {
    const float c = 0.08838834764831845f * 1.4426950408889634f;
    const __bf16* qp = Qg + base + (size_t)(q0 + l31) * D + hi * 8;
#pragma unroll
    for (int dc = 0; dc < 8; ++dc) {
      bf8_t v = *(const bf8_t*)(qp + dc * 16);
#pragma unroll
      for (int j = 0; j < 8; ++j) v[j] = (__bf16)((float)v[j] * c);
      qf[dc] = v;
    }
  }

  f32x16 accO[4];
#pragma unroll
  for (int db = 0; db < 4; ++db)
#pragma unroll
    for (int j = 0; j < 16; ++j) accO[db][j] = 0.f;
  float m_ = -1e30f, l_ = 0.f;

  // staging pointers (per-lane constants + pointer bump per tile)
  const int krow = wave * 16 + (lane >> 4);          // +i*4 per issue
  const __bf16* kgp = Kg + base + (size_t)(kvbase + krow) * D;
  __bf16* klds = &sK[0][0] + (wave * 16) * 128;      // issue i: +i*4*128
  const int vrow = wave * 64 + (lane >> 2);          // +i*16 per issue
  const int vgc = ((lane & 3) ^ ((lane >> 3) & 3)) * 8;  // f(d)=(d>>1)&3, const/lane
  const __bf16* vgp = Vtg + vtbase + (size_t)vrow * 4096 + kvbase + vgc;
  __bf16* vlds = &sVt[0][0] + (wave * 64) * 32;      // issue i: +i*16*32

  auto stageK = [&](int buf, int kv) {
    const __bf16* g = kgp + (size_t)kv * D;
    __bf16* l = klds + buf * (32 * 128);
#pragma unroll
    for (int i = 0; i < 4; ++i) {
      const int gc = (lane & 15) ^ (((lane >> 4) + i * 4) & 7);
      gload_lds16(g + (size_t)(i * 4) * D + gc * 8, l + i * 4 * 128);
    }
  };
  auto stageV = [&](int buf, int kv) {
    const __bf16* g = vgp + kv;
    __bf16* l = vlds + buf * (128 * 32);
#pragma unroll
    for (int i = 0; i < 4; ++i)
      gload_lds16(g + (size_t)(i * 16) * 4096, l + i * 16 * 32);
  };

  stageK(0, 0);
  stageV(0, 0);

  for (int t = 0; t < 32; ++t) {
    const int cur = t & 1;
    __syncthreads();  // drains DMA for buf[cur]; guards buf[cur^1] reuse
    if (t < 31) {
      stageK(cur ^ 1, (t + 1) * 32);
      stageV(cur ^ 1, (t + 1) * 32);
    }

    // QK^T swapped: accS holds S[k][q]; q = l31 (lane-local row),
    // k = (r&3) + 8*(r>>2) + 4*hi.
    f32x16 accS;
#pragma unroll
    for (int j = 0; j < 16; ++j) accS[j] = 0.f;
    const __bf16* kb_ = sK[cur];
    const int kr = l31;
    __builtin_amdgcn_s_setprio(1);
#pragma unroll
    for (int dc = 0; dc < 8; ++dc) {
      bf8_t a = *(const bf8_t*)&kb_[kr * 128 + ((2 * dc + hi) ^ (kr & 7)) * 8];
      accS = MFMA32(a, qf[dc], accS);
    }
    __builtin_amdgcn_s_setprio(0);

    // row max: in-register tree + one cross-half exchange
    float pm = fmaxf(accS[0], accS[1]);
#pragma unroll
    for (int j = 2; j < 16; ++j) pm = fmaxf(pm, accS[j]);
    pm = fmaxf(pm, __shfl_xor(pm, 32));

    // defer-max (T13): rescale only when some row max grows by > 8 (log2)
    if (__ballot(pm > m_ + 8.0f)) {
      const float mn = fmaxf(m_, pm);
      const float sc = exp2f(m_ - mn);
      m_ = mn;
      l_ *= sc;
      if (hi == 0) sW[wave][l31] = sc;
#pragma unroll
      for (int r = 0; r < 16; ++r) {
        const float scr = sW[wave][(r & 3) + 8 * (r >> 2) + 4 * hi];
#pragma unroll
        for (int db = 0; db < 4; ++db) accO[db][r] *= scr;
      }
    }

    // p = 2^(s - m), row sum
    float rs = 0.f;
#pragma unroll
    for (int j = 0; j < 16; ++j) {
      const float p = exp2f(accS[j] - m_);
      accS[j] = p;
      rs += p;
    }
    rs += __shfl_xor(rs, 32);
    l_ += rs;

    // pack P quads: pk[tq] covers k = 8*tq + 4*hi + {0..3}
    unsigned pk[4][2];
#pragma unroll
    for (int tq = 0; tq < 4; ++tq) {
      pk[tq][0] = pk2(accS[4 * tq + 0], accS[4 * tq + 1]);
      pk[tq][1] = pk2(accS[4 * tq + 2], accS[4 * tq + 3]);
    }

    // PV: 2 K=16 slices; A-frag via one lane-pair quad exchange per slice
    const __bf16* vt_ = sVt[cur];
#pragma unroll
    for (int kc = 0; kc < 2; ++kc) {
      const unsigned own0 = hi ? pk[2 * kc + 1][0] : pk[2 * kc][0];
      const unsigned own1 = hi ? pk[2 * kc + 1][1] : pk[2 * kc][1];
      const unsigned snd0 = hi ? pk[2 * kc][0] : pk[2 * kc + 1][0];
      const unsigned snd1 = hi ? pk[2 * kc][1] : pk[2 * kc + 1][1];
      const unsigned rc0 = (unsigned)__shfl_xor((int)snd0, 32);
      const unsigned rc1 = (unsigned)__shfl_xor((int)snd1, 32);
      u32x4 fr;
      fr[0] = hi ? rc0 : own0;
      fr[1] = hi ? rc1 : own1;
      fr[2] = hi ? own0 : rc0;
      fr[3] = hi ? own1 : rc1;
      const bf8_t pa = __builtin_bit_cast(bf8_t, fr);
      __builtin_amdgcn_s_setprio(1);
#pragma unroll
      for (int db = 0; db < 4; ++db) {
        const int dr = db * 32 + l31;
        const int p = (kc * 2 + hi) ^ ((dr >> 1) & 3);
        bf8_t vb = *(const bf8_t*)&vt_[dr * 32 + p * 8];
        accO[db] = MFMA32(pa, vb, accO[db]);
      }
      __builtin_amdgcn_s_setprio(0);
    }
  }

  // partial epilogue: unnormalized O (bf16) + (m,l) per q-row
  const size_t pbase = ((size_t)(z * 16 + bh) * 2048 + q0);
#pragma unroll
  for (int r = 0; r < 16; ++r) {
    const int qr = (r & 3) + 8 * (r >> 2) + 4 * hi;
    __bf16* op = Op + (pbase + qr) * 128 + l31;
#pragma unroll
    for (int db = 0; db < 4; ++db)
      op[db * 32] = (__bf16)(accO[db][r]);
  }
  if (hi == 0) {
    ml[(pbase + l31) * 2 + 0] = m_;
    ml[(pbase + l31) * 2 + 1] = l_;
  }
}

// ---------------------------------------------------------------------------
// Kernel 3b: merge the two KV-half partials.
// O = (O0*w0 + O1*w1) / (l0*w0 + l1*w1), wi = 2^(mi - max(m0,m1)).
// ---------------------------------------------------------------------------
__global__ __launch_bounds__(256) void attn_merge_k(
    const __bf16* __restrict__ Op, const float* __restrict__ ml,
    __bf16* __restrict__ Og) {
  const int bh = blockIdx.x >> 7, qc = blockIdx.x & 127;
  const int t = threadIdx.x;
  const int qr = qc * 16 + (t >> 4);
  const int d0 = (t & 15) * 8;
  const int b = bh >> 3, h = bh & 7;

  const size_t i0 = ((size_t)bh * 2048 + qr);
  const size_t i1 = ((size_t)(16 + bh) * 2048 + qr);
  const float m0 = ml[i0 * 2], l0 = ml[i0 * 2 + 1];
  const float m1 = ml[i1 * 2], l1 = ml[i1 * 2 + 1];
  const float m = fmaxf(m0, m1);
  const float w0 = exp2f(m0 - m), w1 = exp2f(m1 - m);
  const float inv = 1.0f / (l0 * w0 + l1 * w1);

  bf8_t o0 = *(const bf8_t*)(Op + i0 * 128 + d0);
  bf8_t o1 = *(const bf8_t*)(Op + i1 * 128 + d0);
  bf8_t r;
#pragma unroll
  for (int j = 0; j < 8; ++j)
    r[j] = (__bf16)(((float)o0[j] * w0 + (float)o1[j] * w1) * inv);
  *(bf8_t*)(Og + ((size_t)(b * 2048 + qr) * 1024) + h * 128 + d0) = r;
}

// ---------------------------------------------------------------------------
// Kernel 4: output projection + bias + LoRA-up. 64x128 tiles (512 blocks =
// 2 blocks/CU = 2 waves/SIMD; the 128-tile version ran 1 block/CU).
// ---------------------------------------------------------------------------
__global__ __launch_bounds__(256) void gemm_out_k(
    const __bf16* __restrict__ A, const __bf16* __restrict__ Wo,
    const float* __restrict__ bo, const float* __restrict__ lup,
    const float* __restrict__ tmp, float* __restrict__ out) {
  __shared__ __bf16 sA[64 * 64];
  __shared__ __bf16 sB[128 * 64];
  const int bcol = blockIdx.x, brow = blockIdx.y;
  const int K = 1024, N = 1024;
  f32x4 acc[2][4];
  gemm_tile<2>(A + (size_t)brow * 64 * K, Wo + (size_t)bcol * 128 * K, K, sA, sB, acc);

  const int lane = threadIdx.x & 63, wave = threadIdx.x >> 6;
  const int wr = (wave >> 1) * 32, wc = (wave & 1) * 64;
  for (int n = 0; n < 4; ++n) {
    const int col = bcol * 128 + wc + n * 16 + (lane & 15);
    const float bias = bo[col];
    const float u0 = lup[col * 4 + 0], u1 = lup[col * 4 + 1];
    const float u2 = lup[col * 4 + 2], u3 = lup[col * 4 + 3];
    for (int m = 0; m < 2; ++m)
      for (int j = 0; j < 4; ++j) {
        const int row = brow * 64 + wr + m * 16 + (lane >> 4) * 4 + j;
        const float* t = tmp + row * 4;
        float v = acc[m][n][j] + bias + t[0] * u0 + t[1] * u1 + t[2] * u2 + t[3] * u3;
        out[(size_t)row * N + col] = v;
      }
  }
}

// ---------------------------------------------------------------------------
extern "C" void kernel_launch(void* const* d_in, const int* in_sizes, int n_in,
                              void* d_out, int out_size, void* d_ws, size_t ws_size,
                              hipStream_t stream) {
  (void)in_sizes; (void)n_in; (void)out_size; (void)ws_size;
  const float* hs  = (const float*)d_in[0];
  const float* cs  = (const float*)d_in[1];
  const float* Wq  = (const float*)d_in[2];
  const float* Wk  = (const float*)d_in[3];
  const float* Wv  = (const float*)d_in[4];
  const float* Wo  = (const float*)d_in[5];
  const float* bo  = (const float*)d_in[6];
  const float* ldw = (const float*)d_in[7];
  const float* lup = (const float*)d_in[8];
  float* out = (float*)d_out;

  const size_t MD = (size_t)4096 * 1024;   // B*S*D
  const size_t WD = (size_t)1024 * 1024;   // D*D
  __bf16* hsb = (__bf16*)d_ws;
  __bf16* Wqb = hsb + MD;
  __bf16* Wkb = Wqb + WD;
  __bf16* Wvb = Wkb + WD;
  __bf16* Wob = Wvb + WD;
  __bf16* Qb  = Wob + WD;
  __bf16* Kb  = Qb + MD;
  __bf16* Vtb = Kb + MD;   // V^T: [h*128+d][b*2048+s] = [1024][4096]
  __bf16* Ab  = Vtb + MD;
  float*  tmp = (float*)(Ab + MD);              // [4096][4]
  __bf16* Opart = (__bf16*)(tmp + 4096 * 4);    // [2][16][2048][128] bf16
  float*  mlp   = (float*)(Opart + (size_t)2 * 16 * 2048 * 128);  // [2][16][2048][2]

  cvt5_k<<<dim3(2048, 5), 256, 0, stream>>>(hs, Wq, Wk, Wv, Wo,
                                            hsb, Wqb, Wkb, Wvb, Wob);
  gemm_qkv_k<<<dim3(8, 32, 3), 256, 0, stream>>>(hsb, Wqb, Wkb, Wvb, Qb, Kb, Vtb);
  lora_down_k<<<dim3(1024), 256, 0, stream>>>(cs, ldw, tmp);
  flash_attn_k<<<dim3(32, 16, 2), 128, 0, stream>>>(Qb, Kb, Vtb, Opart, mlp);
  attn_merge_k<<<dim3(2048), 256, 0, stream>>>(Opart, mlp, Ab);
  gemm_out_k<<<dim3(8, 64), 256, 0, stream>>>(Ab, Wob, bo, lup, tmp, out);
}